// Round 6
// baseline (388.396 us; speedup 1.0000x reference)
//
#include <hip/hip_runtime.h>
#include <hip/hip_bf16.h>

#define EPS 1e-5f

typedef __attribute__((ext_vector_type(8))) short bf16x8;
typedef __attribute__((ext_vector_type(4))) float f32x4;

#define WAITVM4 asm volatile("s_waitcnt vmcnt(4)" ::: "memory")
#define WAITVM0 asm volatile("s_waitcnt vmcnt(0)" ::: "memory")
#define BAR()   __builtin_amdgcn_s_barrier()

// ---- async global->LDS, 16B per lane, linear dest (wave-uniform base + lane*16)
__device__ __forceinline__ void gld_lds16(const void* g, void* l) {
    __builtin_amdgcn_global_load_lds(
        (const __attribute__((address_space(1))) unsigned int*)g,
        (__attribute__((address_space(3))) unsigned int*)l, 16, 0, 0);
}

// ---------------- pre-pass: weights [256][256][3][3] f32 -> [256][9][256] bf16
__global__ __launch_bounds__(256) void wt_transpose_bf16(
    const float* __restrict__ w, __hip_bfloat16* __restrict__ wt)
{
    const int co = blockIdx.x;
    const int ci = threadIdx.x;
    const float* wp = w + (size_t)co * 2304 + (size_t)ci * 9;
    __hip_bfloat16* wo = wt + (size_t)co * 2304 + ci;
#pragma unroll
    for (int j = 0; j < 9; ++j)
        wo[(size_t)j * 256] = __float2bfloat16(wp[j]);
}

// ---------------- pre-pass: f32 -> bf16 elementwise (for w_h1)
__global__ __launch_bounds__(256) void f32_to_bf16(
    const float* __restrict__ x, __hip_bfloat16* __restrict__ y, int n)
{
    int i = blockIdx.x * 256 + threadIdx.x;
    if (i < n) y[i] = __float2bfloat16(x[i]);
}

// ---------------- pre-pass: x [B][256][P] f32 -> xt [B][P][256] bf16 (NHWC)
__global__ __launch_bounds__(256) void nchw_to_nhwc_bf16(
    const float* __restrict__ x, __hip_bfloat16* __restrict__ xt, int P)
{
    const int b   = blockIdx.z;
    const int ci0 = blockIdx.y * 32;
    const int p0  = blockIdx.x * 32;
    const int tx  = threadIdx.x & 31, ty = threadIdx.x >> 5; // 32x8
    __shared__ float t[32][33];
    const float* xb = x + ((size_t)b * 256 + ci0) * P;
#pragma unroll
    for (int r = 0; r < 4; ++r) {
        int ci = ty + r * 8;
        int p  = p0 + tx;
        if (p < P) t[ci][tx] = xb[(size_t)ci * P + p];
    }
    __syncthreads();
    __hip_bfloat16* xo = xt + (size_t)b * P * 256 + ci0;
#pragma unroll
    for (int r = 0; r < 4; ++r) {
        int p = p0 + ty + r * 8;
        if (p < P) xo[(size_t)p * 256 + tx] = __float2bfloat16(t[tx][ty + r * 8]);
    }
}

// ---------------- conv3x3 via MFMA implicit GEMM + fused BN+ReLU, NHWC out ----
// M = 256 (co), N = B*POUT (pixels), K = 2304 (256 ci x 9 taps)
// tile 128x128, 4 waves, BK=32. Counted-vmcnt pipeline: 3 LDS buffers (48KB ->
// 3 blocks/CU), depth-2 prefetch, one raw s_barrier per K-step, vmcnt(4) in
// the main loop (T3+T4). LDS slot-swizzle kills the 8-way bank conflict:
// chunk (row, seg) stored at slot seg ^ ((row>>1)&3)  [rule #21: linear dest
// + inverse-swizzled global source + swizzled read].
template<int HIN, int WIN>
__global__ __launch_bounds__(256) void conv3x3_mfma(
    const __hip_bfloat16* __restrict__ xt,  // [B][HIN][WIN][256]
    const __hip_bfloat16* __restrict__ wt,  // [256][9][256]
    const float* __restrict__ g, const float* __restrict__ bb,
    const float* __restrict__ mm_, const float* __restrict__ vv,
    __hip_bfloat16* __restrict__ y)         // NHWC: [B*POUT][256]
{
    constexpr int HOUT = HIN - 2, WOUT = WIN - 2, POUT = HOUT * WOUT;
    const int n0  = blockIdx.x * 128;
    const int co0 = blockIdx.y * 128;
    const int tid = threadIdx.x;
    const int wid = tid >> 6, lane = tid & 63;
    const int wr = wid >> 1, wc = wid & 1;

    // 3 buffers x (A 8KB + B 8KB) = 48 KB
    __shared__ __align__(16) __hip_bfloat16 lA[3 * 4096];
    __shared__ __align__(16) __hip_bfloat16 lB[3 * 4096];

    const int row0 = wid * 16 + (lane >> 2);
    const int row1 = row0 + 64;
    // swizzled source seg: slot (lane&3) at row holds data seg = slot ^ ((row>>1)&3)
    // (row0>>1)&3 == (lane>>3)&3 because wid*8 ≡ 0 (mod 4); row1 = row0+64 same.
    const int seg  = (lane & 3) ^ ((lane >> 3) & 3);

    const size_t wbase0 = (size_t)(co0 + row0) * 2304 + seg * 8;
    const size_t wbase1 = (size_t)(co0 + row1) * 2304 + seg * 8;

    int n_r0 = n0 + row0;
    int b_r0 = n_r0 / POUT, p_r0 = n_r0 % POUT;
    int oy0 = p_r0 / WOUT, ox0 = p_r0 % WOUT;
    const size_t xbase0 = (((size_t)b_r0 * HIN + oy0) * WIN + ox0) * 256 + seg * 8;
    int n_r1 = n0 + row1;
    int b_r1 = n_r1 / POUT, p_r1 = n_r1 % POUT;
    int oy1 = p_r1 / WOUT, ox1 = p_r1 % WOUT;
    const size_t xbase1 = (((size_t)b_r1 * HIN + oy1) * WIN + ox1) * 256 + seg * 8;

    // stage K-step (c0, j) into buffer sel (4 gld instrs -> vmcnt +4)
    auto STAGE = [&](int c0, int j, int sel) {
        char* a0 = (char*)lA + sel * 8192 + wid * 1024;
        char* b0 = (char*)lB + sel * 8192 + wid * 1024;
        const int woff = j * 256 + c0;
        gld_lds16(wt + wbase0 + woff, a0);
        gld_lds16(wt + wbase1 + woff, a0 + 4096);
        const int xoff = ((j / 3) * WIN + (j % 3)) * 256 + c0;
        gld_lds16(xt + xbase0 + xoff, b0);
        gld_lds16(xt + xbase1 + xoff, b0 + 4096);
    };

    f32x4 acc[4][4];
#pragma unroll
    for (int i = 0; i < 4; ++i)
#pragma unroll
        for (int j = 0; j < 4; ++j)
            acc[i][j] = f32x4{0.f, 0.f, 0.f, 0.f};

    const int l15 = lane & 15, l16 = lane >> 4;
    // swizzled read slot; (row>>1)&3 == (l15>>1)&3 for row = w*64 + l15 + i*16
    const int slot = l16 ^ ((l15 >> 1) & 3);
    const int aoff = (wr * 64 + l15) * 32 + slot * 8;  // elems within buffer
    const int boff = (wc * 64 + l15) * 32 + slot * 8;

    auto COMPUTE = [&](int sel) {
        const int base = sel * 4096;
        bf16x8 a[4], b[4];
#pragma unroll
        for (int i = 0; i < 4; ++i)
            a[i] = *reinterpret_cast<const bf16x8*>(&lA[base + aoff + i * 512]);
#pragma unroll
        for (int i = 0; i < 4; ++i)
            b[i] = *reinterpret_cast<const bf16x8*>(&lB[base + boff + i * 512]);
#pragma unroll
        for (int i = 0; i < 4; ++i)
#pragma unroll
            for (int jj = 0; jj < 4; ++jj)
                acc[i][jj] = __builtin_amdgcn_mfma_f32_16x16x32_bf16(
                    a[i], b[jj], acc[i][jj], 0, 0, 0);
    };

    // prologue: stage steps 0,1 (8 gld in flight)
    STAGE(0, 0, 0);
    STAGE(0, 1, 1);
    int c0s = 0, js = 2;  // stage cursor for step t+2

    // main loop: t = 0..68 (72 K-steps total; 3 tail steps peeled)
    for (int tt = 0; tt < 23; ++tt) {
#pragma unroll
        for (int u = 0; u < 3; ++u) {
            WAITVM4;       // stage(t) complete; stage(t+1) stays in flight
            BAR();
            STAGE(c0s, js, (u + 2) % 3);  // step t+2 -> buf (t+2)%3
            ++js; if (js == 9) { js = 0; c0s += 32; }
            COMPUTE(u);
        }
    }
    // tail: t = 69,70,71
    WAITVM4; BAR(); STAGE(c0s, js, 2); COMPUTE(0);  // t=69 stages step 71
    WAITVM4; BAR(); COMPUTE(1);                     // t=70 (71 in flight)
    WAITVM0; BAR(); COMPUTE(2);                     // t=71

    // epilogue: D[m=(lane>>4)*4+r][n=lane&15]; NHWC store y[n][co]
#pragma unroll
    for (int i = 0; i < 4; ++i) {
#pragma unroll
        for (int r = 0; r < 4; ++r) {
            const int co = co0 + wr * 64 + i * 16 + l16 * 4 + r;
            const float sc = g[co] * rsqrtf(vv[co] + EPS);
            const float sh = bb[co] - mm_[co] * sc;
#pragma unroll
            for (int jj = 0; jj < 4; ++jj) {
                const int n = n0 + wc * 64 + jj * 16 + l15;
                const float v = fmaf(acc[i][jj][r], sc, sh);
                y[(size_t)n * 256 + co] = __float2bfloat16(fmaxf(v, 0.f));
            }
        }
    }
}

// ---------------- depthwise xcorr 5x5, NHWC, fully coalesced ----------------
__global__ __launch_bounds__(256) void xcorr_dw_nhwc(
    const __hip_bfloat16* __restrict__ s,  // [B][841][256]
    const __hip_bfloat16* __restrict__ k,  // [B][25][256]
    __hip_bfloat16* __restrict__ f)        // [B][625][256]
{
    const int py = blockIdx.x, b = blockIdx.y, c = threadIdx.x;
    const __hip_bfloat16* sp = s + ((size_t)b * 841) * 256 + c;
    const __hip_bfloat16* kp = k + ((size_t)b * 25) * 256 + c;

    float acc[25];
#pragma unroll
    for (int i = 0; i < 25; ++i) acc[i] = 0.f;

    for (int ky = 0; ky < 5; ++ky) {
        const __hip_bfloat16* srp = sp + (size_t)(py + ky) * 29 * 256;
        float srow[29];
#pragma unroll
        for (int rx = 0; rx < 29; ++rx) srow[rx] = __bfloat162float(srp[(size_t)rx * 256]);
#pragma unroll
        for (int kx = 0; kx < 5; ++kx) {
            const float kv = __bfloat162float(kp[(size_t)(ky * 5 + kx) * 256]);
#pragma unroll
            for (int px = 0; px < 25; ++px)
                acc[px] = fmaf(srow[px + kx], kv, acc[px]);
        }
    }

    __hip_bfloat16* fp = f + ((size_t)b * 625 + (size_t)py * 25) * 256 + c;
#pragma unroll
    for (int px = 0; px < 25; ++px) fp[(size_t)px * 256] = __float2bfloat16(acc[px]);
}

// ---------------- head layer 1: 1x1 conv via MFMA + BN + ReLU, NHWC ----------
// GEMM: M=256(co), N=80000(pix), K=256(ci); 3-buffer counted-vmcnt pipeline,
// same LDS slot-swizzle, 8 K-steps straight-line unrolled.
__global__ __launch_bounds__(256) void head1_mfma(
    const __hip_bfloat16* __restrict__ f,   // [N][256]
    const __hip_bfloat16* __restrict__ w1,  // [256][256] bf16
    const float* __restrict__ g, const float* __restrict__ bb,
    const float* __restrict__ mm_, const float* __restrict__ vv,
    __hip_bfloat16* __restrict__ h)         // [N][256]
{
    const int n0  = blockIdx.x * 128;
    const int co0 = blockIdx.y * 128;
    const int tid = threadIdx.x;
    const int wid = tid >> 6, lane = tid & 63;
    const int wr = wid >> 1, wc = wid & 1;

    __shared__ __align__(16) __hip_bfloat16 lA[3 * 4096];
    __shared__ __align__(16) __hip_bfloat16 lB[3 * 4096];

    const int row0 = wid * 16 + (lane >> 2);
    const int row1 = row0 + 64;
    const int seg  = (lane & 3) ^ ((lane >> 3) & 3);

    const size_t wbase0 = (size_t)(co0 + row0) * 256 + seg * 8;
    const size_t wbase1 = (size_t)(co0 + row1) * 256 + seg * 8;
    const size_t xbase0 = (size_t)(n0 + row0) * 256 + seg * 8;
    const size_t xbase1 = (size_t)(n0 + row1) * 256 + seg * 8;

    auto STAGE = [&](int c0, int sel) {
        char* a0 = (char*)lA + sel * 8192 + wid * 1024;
        char* b0 = (char*)lB + sel * 8192 + wid * 1024;
        gld_lds16(w1 + wbase0 + c0, a0);
        gld_lds16(w1 + wbase1 + c0, a0 + 4096);
        gld_lds16(f + xbase0 + c0, b0);
        gld_lds16(f + xbase1 + c0, b0 + 4096);
    };

    f32x4 acc[4][4];
#pragma unroll
    for (int i = 0; i < 4; ++i)
#pragma unroll
        for (int j = 0; j < 4; ++j)
            acc[i][j] = f32x4{0.f, 0.f, 0.f, 0.f};

    const int l15 = lane & 15, l16 = lane >> 4;
    const int slot = l16 ^ ((l15 >> 1) & 3);
    const int aoff = (wr * 64 + l15) * 32 + slot * 8;
    const int boff = (wc * 64 + l15) * 32 + slot * 8;

    auto COMPUTE = [&](int sel) {
        const int base = sel * 4096;
        bf16x8 a[4], b[4];
#pragma unroll
        for (int i = 0; i < 4; ++i)
            a[i] = *reinterpret_cast<const bf16x8*>(&lA[base + aoff + i * 512]);
#pragma unroll
        for (int i = 0; i < 4; ++i)
            b[i] = *reinterpret_cast<const bf16x8*>(&lB[base + boff + i * 512]);
#pragma unroll
        for (int i = 0; i < 4; ++i)
#pragma unroll
            for (int jj = 0; jj < 4; ++jj)
                acc[i][jj] = __builtin_amdgcn_mfma_f32_16x16x32_bf16(
                    a[i], b[jj], acc[i][jj], 0, 0, 0);
    };

    STAGE(0, 0); STAGE(32, 1);                        // steps 0,1
    WAITVM4; BAR(); STAGE(64,  2); COMPUTE(0);        // t=0
    WAITVM4; BAR(); STAGE(96,  0); COMPUTE(1);        // t=1
    WAITVM4; BAR(); STAGE(128, 1); COMPUTE(2);        // t=2
    WAITVM4; BAR(); STAGE(160, 2); COMPUTE(0);        // t=3
    WAITVM4; BAR(); STAGE(192, 0); COMPUTE(1);        // t=4
    WAITVM4; BAR(); STAGE(224, 1); COMPUTE(2);        // t=5
    WAITVM4; BAR(); COMPUTE(0);                       // t=6 (224 in flight)
    WAITVM0; BAR(); COMPUTE(1);                       // t=7

#pragma unroll
    for (int i = 0; i < 4; ++i) {
#pragma unroll
        for (int r = 0; r < 4; ++r) {
            const int co = co0 + wr * 64 + i * 16 + l16 * 4 + r;
            const float sc = g[co] * rsqrtf(vv[co] + EPS);
            const float sh = bb[co] - mm_[co] * sc;
#pragma unroll
            for (int jj = 0; jj < 4; ++jj) {
                const int n = n0 + wc * 64 + jj * 16 + l15;
                const float v = fmaf(acc[i][jj][r], sc, sh);
                h[(size_t)n * 256 + co] = __float2bfloat16(fmaxf(v, 0.f));
            }
        }
    }
}

// ---------------- head layer 2: 1x1 conv (256 -> 10) + bias, NCHW out --------
__global__ __launch_bounds__(256) void head2(
    const __hip_bfloat16* __restrict__ h,  // [N][256]
    const float* __restrict__ w2,          // [10][256]
    const float* __restrict__ b2,          // [10]
    float* __restrict__ out)               // [B][10][25][25]
{
    const int py = blockIdx.x, b = blockIdx.y;
    __shared__ __hip_bfloat16 lh[25][258];
    __shared__ float lw[10][256];

    const __hip_bfloat16* hp = h + ((size_t)b * 625 + (size_t)py * 25) * 256;
    for (int i = threadIdx.x; i < 25 * 256; i += 256) {
        int px = i >> 8, c = i & 255;
        lh[px][c] = hp[i];
    }
    for (int i = threadIdx.x; i < 10 * 256; i += 256)
        lw[i >> 8][i & 255] = w2[i];
    __syncthreads();

    if (threadIdx.x < 250) {
        const int o = threadIdx.x / 25, px = threadIdx.x % 25;
        float a = b2[o];
        for (int c = 0; c < 256; ++c)
            a = fmaf(__bfloat162float(lh[px][c]), lw[o][c], a);
        out[(((size_t)b * 10 + o) * 25 + py) * 25 + px] = a;
    }
}

extern "C" void kernel_launch(void* const* d_in, const int* in_sizes, int n_in,
                              void* d_out, int out_size, void* d_ws, size_t ws_size,
                              hipStream_t stream) {
    const float* kernel = (const float*)d_in[0];   // [128,256,7,7]
    const float* search = (const float*)d_in[1];   // [128,256,31,31]
    const float* w_ck   = (const float*)d_in[2];
    const float* g1 = (const float*)d_in[3];
    const float* b1 = (const float*)d_in[4];
    const float* m1 = (const float*)d_in[5];
    const float* v1 = (const float*)d_in[6];
    const float* w_cs   = (const float*)d_in[7];
    const float* g2 = (const float*)d_in[8];
    const float* b2 = (const float*)d_in[9];
    const float* m2 = (const float*)d_in[10];
    const float* v2 = (const float*)d_in[11];
    const float* w_h1   = (const float*)d_in[12];
    const float* g3 = (const float*)d_in[13];
    const float* b3 = (const float*)d_in[14];
    const float* m3 = (const float*)d_in[15];
    const float* v3 = (const float*)d_in[16];
    const float* w_h2   = (const float*)d_in[17];
    const float* b_h2   = (const float*)d_in[18];

    float* out = (float*)d_out;

    // ws layout (bf16 elements):
    //  y1    [128*25*256]  NHWC @ 0         (819200)
    //  y2    [128*841*256] NHWC @ 819200    (27557888) -> 28377088
    //  wt_ck [256*9*256]        @ 28377088  (589824)   -> 28966912
    //  wt_cs [256*9*256]        @ 28966912  (589824)   -> 29556736
    //  wh1   [256*256]          @ 29556736  (65536)    -> 29622272
    //  xt_k  [128*49*256]       @ 29622272  (1605632)  -> 31227904
    //  xt_s  [128*961*256]      @ 31227904  (31490048) -> 62717952 (125.4 MB)
    //  feat  [80000*256]   NHWC @ 29622272  (reuses xt region after convs)
    //  h     [80000*256]   NHWC @ 819200    (reuses y2 after xcorr)
    __hip_bfloat16* ws = (__hip_bfloat16*)d_ws;
    __hip_bfloat16* y1    = ws;
    __hip_bfloat16* y2    = ws + (size_t)819200;
    __hip_bfloat16* wt_ck = ws + (size_t)28377088;
    __hip_bfloat16* wt_cs = ws + (size_t)28966912;
    __hip_bfloat16* wh1   = ws + (size_t)29556736;
    __hip_bfloat16* xt_k  = ws + (size_t)29622272;
    __hip_bfloat16* xt_s  = ws + (size_t)31227904;
    __hip_bfloat16* feat  = ws + (size_t)29622272;
    __hip_bfloat16* h     = ws + (size_t)819200;

    (void)in_sizes; (void)n_in; (void)out_size; (void)ws_size;

    // pre-passes
    wt_transpose_bf16<<<256, 256, 0, stream>>>(w_ck, wt_ck);
    wt_transpose_bf16<<<256, 256, 0, stream>>>(w_cs, wt_cs);
    f32_to_bf16<<<256, 256, 0, stream>>>(w_h1, wh1, 65536);
    nchw_to_nhwc_bf16<<<dim3(2, 8, 128), 256, 0, stream>>>(kernel, xt_k, 49);
    nchw_to_nhwc_bf16<<<dim3(31, 8, 128), 256, 0, stream>>>(search, xt_s, 961);

    // convs (MFMA implicit GEMM), NHWC outputs
    conv3x3_mfma<7, 7><<<dim3(25, 2), 256, 0, stream>>>(
        xt_k, wt_ck, g1, b1, m1, v1, y1);
    conv3x3_mfma<31, 31><<<dim3(841, 2), 256, 0, stream>>>(
        xt_s, wt_cs, g2, b2, m2, v2, y2);

    // depthwise xcorr -> feat NHWC
    xcorr_dw_nhwc<<<dim3(25, 128), 256, 0, stream>>>(y2, y1, feat);

    // head
    head1_mfma<<<dim3(625, 2), 256, 0, stream>>>(feat, wh1, g3, b3, m3, v3, h);
    head2<<<dim3(25, 128), 256, 0, stream>>>(h, w_h2, b_h2, out);
}

// Round 7
// 371.087 us; speedup vs baseline: 1.0466x; 1.0466x over previous
//
#include <hip/hip_runtime.h>
#include <hip/hip_bf16.h>

#define EPS 1e-5f

typedef __attribute__((ext_vector_type(8))) short bf16x8;
typedef __attribute__((ext_vector_type(4))) float f32x4;
typedef __attribute__((ext_vector_type(4))) unsigned short u16x4;

#define WAITVM6 asm volatile("s_waitcnt vmcnt(6)" ::: "memory")
#define WAITVM0 asm volatile("s_waitcnt vmcnt(0)" ::: "memory")
#define BAR()   __builtin_amdgcn_s_barrier()

// ---- async global->LDS, 16B per lane, linear dest (wave-uniform base + lane*16)
__device__ __forceinline__ void gld_lds16(const void* g, void* l) {
    __builtin_amdgcn_global_load_lds(
        (const __attribute__((address_space(1))) unsigned int*)g,
        (__attribute__((address_space(3))) unsigned int*)l, 16, 0, 0);
}

// ---------------- pre-pass: weights [256][256][3][3] f32 -> [256][9][256] bf16
__global__ __launch_bounds__(256) void wt_transpose_bf16(
    const float* __restrict__ w, __hip_bfloat16* __restrict__ wt)
{
    const int co = blockIdx.x;
    const int ci = threadIdx.x;
    const float* wp = w + (size_t)co * 2304 + (size_t)ci * 9;
    __hip_bfloat16* wo = wt + (size_t)co * 2304 + ci;
#pragma unroll
    for (int j = 0; j < 9; ++j)
        wo[(size_t)j * 256] = __float2bfloat16(wp[j]);
}

// ---------------- pre-pass: f32 -> bf16 elementwise (for w_h1)
__global__ __launch_bounds__(256) void f32_to_bf16(
    const float* __restrict__ x, __hip_bfloat16* __restrict__ y, int n)
{
    int i = blockIdx.x * 256 + threadIdx.x;
    if (i < n) y[i] = __float2bfloat16(x[i]);
}

// ---------------- pre-pass: x [B][256][P] f32 -> xt [B][P][256] bf16 (NHWC)
__global__ __launch_bounds__(256) void nchw_to_nhwc_bf16(
    const float* __restrict__ x, __hip_bfloat16* __restrict__ xt, int P)
{
    const int b   = blockIdx.z;
    const int ci0 = blockIdx.y * 32;
    const int p0  = blockIdx.x * 32;
    const int tx  = threadIdx.x & 31, ty = threadIdx.x >> 5; // 32x8
    __shared__ float t[32][33];
    const float* xb = x + ((size_t)b * 256 + ci0) * P;
#pragma unroll
    for (int r = 0; r < 4; ++r) {
        int ci = ty + r * 8;
        int p  = p0 + tx;
        if (p < P) t[ci][tx] = xb[(size_t)ci * P + p];
    }
    __syncthreads();
    __hip_bfloat16* xo = xt + (size_t)b * P * 256 + ci0;
#pragma unroll
    for (int r = 0; r < 4; ++r) {
        int p = p0 + ty + r * 8;
        if (p < P) xo[(size_t)p * 256 + tx] = __float2bfloat16(t[tx][ty + r * 8]);
    }
}

// ---------------- conv3x3 via MFMA implicit GEMM + fused BN+ReLU, NHWC out ----
// M = 256 (co, FULL), N = B*POUT (pixels), K = 2304 (256 ci x 9 taps)
// Block tile 256(M) x 128(N), 4 waves in 2(M) x 2(N); wave tile 128x64 =
// 8x4 fragments, 32 MFMA / wave / K-step (BK=32). Counted-vmcnt pipeline:
// 3 LDS buffers (72 KB), depth-2 prefetch, one s_barrier per K-step,
// vmcnt(6) in the main loop (6 gld_lds / wave / step). Slot-swizzled LDS
// (chunk (row,seg) at slot seg^((row>>1)&3)) keeps ds_read conflict-free.
template<int HIN, int WIN>
__global__ __launch_bounds__(256, 2) void conv3x3_mfma(
    const __hip_bfloat16* __restrict__ xt,  // [B][HIN][WIN][256]
    const __hip_bfloat16* __restrict__ wt,  // [256][9][256]
    const float* __restrict__ g, const float* __restrict__ bb,
    const float* __restrict__ mm_, const float* __restrict__ vv,
    __hip_bfloat16* __restrict__ y)         // NHWC: [B*POUT][256]
{
    constexpr int HOUT = HIN - 2, WOUT = WIN - 2, POUT = HOUT * WOUT;
    const int n0  = blockIdx.x * 128;
    const int tid = threadIdx.x;
    const int wid = tid >> 6, lane = tid & 63;
    const int wr = wid >> 1, wc = wid & 1;   // wave M-half (128 rows) / N-half (64 px)

    // 3 bufs: A 256x32 (16KB) each, B 128x32 (8KB) each -> 72 KB
    __shared__ __align__(16) __hip_bfloat16 lA[3 * 8192];
    __shared__ __align__(16) __hip_bfloat16 lB[3 * 4096];

    const int srow = wid * 16 + (lane >> 2);        // staging row within 64-strip
    const int seg  = (lane & 3) ^ ((lane >> 3) & 3); // inverse-swizzled source seg

    // A: co rows q*64 + srow (q=0..3)
    const size_t wbase = (size_t)srow * 2304 + seg * 8;
    // B: pixel rows n0 + q*64 + srow (q=0..1)
    int n_r0 = n0 + srow;
    int b_r0 = n_r0 / POUT, p_r0 = n_r0 % POUT;
    int oy0 = p_r0 / WOUT, ox0 = p_r0 % WOUT;
    const size_t xbase0 = (((size_t)b_r0 * HIN + oy0) * WIN + ox0) * 256 + seg * 8;
    int n_r1 = n_r0 + 64;
    int b_r1 = n_r1 / POUT, p_r1 = n_r1 % POUT;
    int oy1 = p_r1 / WOUT, ox1 = p_r1 % WOUT;
    const size_t xbase1 = (((size_t)b_r1 * HIN + oy1) * WIN + ox1) * 256 + seg * 8;

    // stage K-step (c0, j) into buffer sel: 6 gld_lds16 per wave
    auto STAGE = [&](int c0, int j, int sel) {
        char* a0 = (char*)lA + sel * 16384 + wid * 1024;
        char* b0 = (char*)lB + sel * 8192  + wid * 1024;
        const int woff = j * 256 + c0;
        gld_lds16(wt + wbase + woff,                a0);
        gld_lds16(wt + wbase + 64 * 2304 + woff,    a0 + 4096);
        gld_lds16(wt + wbase + 128 * 2304 + woff,   a0 + 8192);
        gld_lds16(wt + wbase + 192 * 2304 + woff,   a0 + 12288);
        const int xoff = ((j / 3) * WIN + (j % 3)) * 256 + c0;
        gld_lds16(xt + xbase0 + xoff, b0);
        gld_lds16(xt + xbase1 + xoff, b0 + 4096);
    };

    f32x4 acc[8][4];
#pragma unroll
    for (int i = 0; i < 8; ++i)
#pragma unroll
        for (int j = 0; j < 4; ++j)
            acc[i][j] = f32x4{0.f, 0.f, 0.f, 0.f};

    const int l15 = lane & 15, l16 = lane >> 4;
    const int slot = l16 ^ ((l15 >> 1) & 3);
    const int aoff = (wr * 128 + l15) * 32 + slot * 8;  // elems within A buffer
    const int boff = (wc * 64  + l15) * 32 + slot * 8;  // elems within B buffer

    auto COMPUTE = [&](int sel) {
        const int abase = sel * 8192;
        const int bbase = sel * 4096;
        bf16x8 b[4];
#pragma unroll
        for (int j = 0; j < 4; ++j)
            b[j] = *reinterpret_cast<const bf16x8*>(&lB[bbase + boff + j * 512]);
#pragma unroll
        for (int i = 0; i < 8; ++i) {
            bf16x8 a = *reinterpret_cast<const bf16x8*>(&lA[abase + aoff + i * 512]);
#pragma unroll
            for (int j = 0; j < 4; ++j)
                acc[i][j] = __builtin_amdgcn_mfma_f32_16x16x32_bf16(
                    a, b[j], acc[i][j], 0, 0, 0);
        }
    };

    // prologue: stage steps 0,1 (12 gld in flight)
    STAGE(0, 0, 0);
    STAGE(0, 1, 1);
    int c0s = 0, js = 2;  // cursor for step t+2

    // main loop: t = 0..68 of 72 K-steps (step t -> buf t%3)
    for (int tt = 0; tt < 23; ++tt) {
#pragma unroll
        for (int u = 0; u < 3; ++u) {
            WAITVM6;       // stage(t) complete; stage(t+1) stays in flight
            BAR();
            STAGE(c0s, js, (u + 2) % 3);
            ++js; if (js == 9) { js = 0; c0s += 32; }
            COMPUTE(u);
        }
    }
    // tail: t = 69,70,71
    WAITVM6; BAR(); STAGE(c0s, js, 2); COMPUTE(0);  // t=69 stages step 71
    WAITVM6; BAR(); COMPUTE(1);                     // t=70 (71 in flight)
    WAITVM0; BAR(); COMPUTE(2);                     // t=71

    // epilogue: frag (i,jj): co = wr*128+i*16+l16*4+r, n = n0+wc*64+jj*16+l15
    // pack r=0..3 (consecutive co) into one 8B store
#pragma unroll
    for (int i = 0; i < 8; ++i) {
        const int co_b = wr * 128 + i * 16 + l16 * 4;
        float sc[4], sh[4];
#pragma unroll
        for (int r = 0; r < 4; ++r) {
            sc[r] = g[co_b + r] * rsqrtf(vv[co_b + r] + EPS);
            sh[r] = bb[co_b + r] - mm_[co_b + r] * sc[r];
        }
#pragma unroll
        for (int jj = 0; jj < 4; ++jj) {
            const int n = n0 + wc * 64 + jj * 16 + l15;
            u16x4 o;
#pragma unroll
            for (int r = 0; r < 4; ++r) {
                const float v = fmaxf(fmaf(acc[i][jj][r], sc[r], sh[r]), 0.f);
                __hip_bfloat16 hv = __float2bfloat16(v);
                o[r] = *reinterpret_cast<unsigned short*>(&hv);
            }
            *reinterpret_cast<u16x4*>(&y[(size_t)n * 256 + co_b]) = o;
        }
    }
}

// ---------------- depthwise xcorr 5x5, NHWC, fully coalesced ----------------
__global__ __launch_bounds__(256) void xcorr_dw_nhwc(
    const __hip_bfloat16* __restrict__ s,  // [B][841][256]
    const __hip_bfloat16* __restrict__ k,  // [B][25][256]
    __hip_bfloat16* __restrict__ f)        // [B][625][256]
{
    const int py = blockIdx.x, b = blockIdx.y, c = threadIdx.x;
    const __hip_bfloat16* sp = s + ((size_t)b * 841) * 256 + c;
    const __hip_bfloat16* kp = k + ((size_t)b * 25) * 256 + c;

    float acc[25];
#pragma unroll
    for (int i = 0; i < 25; ++i) acc[i] = 0.f;

    for (int ky = 0; ky < 5; ++ky) {
        const __hip_bfloat16* srp = sp + (size_t)(py + ky) * 29 * 256;
        float srow[29];
#pragma unroll
        for (int rx = 0; rx < 29; ++rx) srow[rx] = __bfloat162float(srp[(size_t)rx * 256]);
#pragma unroll
        for (int kx = 0; kx < 5; ++kx) {
            const float kv = __bfloat162float(kp[(size_t)(ky * 5 + kx) * 256]);
#pragma unroll
            for (int px = 0; px < 25; ++px)
                acc[px] = fmaf(srow[px + kx], kv, acc[px]);
        }
    }

    __hip_bfloat16* fp = f + ((size_t)b * 625 + (size_t)py * 25) * 256 + c;
#pragma unroll
    for (int px = 0; px < 25; ++px) fp[(size_t)px * 256] = __float2bfloat16(acc[px]);
}

// ---------------- head layer 1: 1x1 conv via MFMA + BN + ReLU, NHWC ----------
// GEMM: M=256(co, FULL), N=80000(pix), K=256(ci). Same 256x128 / 8x4-frag
// structure, 8 K-steps straight-line unrolled.
__global__ __launch_bounds__(256, 2) void head1_mfma(
    const __hip_bfloat16* __restrict__ f,   // [N][256]
    const __hip_bfloat16* __restrict__ w1,  // [256][256] bf16
    const float* __restrict__ g, const float* __restrict__ bb,
    const float* __restrict__ mm_, const float* __restrict__ vv,
    __hip_bfloat16* __restrict__ h)         // [N][256]
{
    const int n0  = blockIdx.x * 128;
    const int tid = threadIdx.x;
    const int wid = tid >> 6, lane = tid & 63;
    const int wr = wid >> 1, wc = wid & 1;

    __shared__ __align__(16) __hip_bfloat16 lA[3 * 8192];
    __shared__ __align__(16) __hip_bfloat16 lB[3 * 4096];

    const int srow = wid * 16 + (lane >> 2);
    const int seg  = (lane & 3) ^ ((lane >> 3) & 3);

    const size_t wbase  = (size_t)srow * 256 + seg * 8;
    const size_t xbase0 = (size_t)(n0 + srow) * 256 + seg * 8;
    const size_t xbase1 = (size_t)(n0 + srow + 64) * 256 + seg * 8;

    auto STAGE = [&](int c0, int sel) {
        char* a0 = (char*)lA + sel * 16384 + wid * 1024;
        char* b0 = (char*)lB + sel * 8192  + wid * 1024;
        gld_lds16(w1 + wbase + c0,              a0);
        gld_lds16(w1 + wbase + 64 * 256 + c0,   a0 + 4096);
        gld_lds16(w1 + wbase + 128 * 256 + c0,  a0 + 8192);
        gld_lds16(w1 + wbase + 192 * 256 + c0,  a0 + 12288);
        gld_lds16(f + xbase0 + c0, b0);
        gld_lds16(f + xbase1 + c0, b0 + 4096);
    };

    f32x4 acc[8][4];
#pragma unroll
    for (int i = 0; i < 8; ++i)
#pragma unroll
        for (int j = 0; j < 4; ++j)
            acc[i][j] = f32x4{0.f, 0.f, 0.f, 0.f};

    const int l15 = lane & 15, l16 = lane >> 4;
    const int slot = l16 ^ ((l15 >> 1) & 3);
    const int aoff = (wr * 128 + l15) * 32 + slot * 8;
    const int boff = (wc * 64  + l15) * 32 + slot * 8;

    auto COMPUTE = [&](int sel) {
        const int abase = sel * 8192;
        const int bbase = sel * 4096;
        bf16x8 b[4];
#pragma unroll
        for (int j = 0; j < 4; ++j)
            b[j] = *reinterpret_cast<const bf16x8*>(&lB[bbase + boff + j * 512]);
#pragma unroll
        for (int i = 0; i < 8; ++i) {
            bf16x8 a = *reinterpret_cast<const bf16x8*>(&lA[abase + aoff + i * 512]);
#pragma unroll
            for (int j = 0; j < 4; ++j)
                acc[i][j] = __builtin_amdgcn_mfma_f32_16x16x32_bf16(
                    a, b[j], acc[i][j], 0, 0, 0);
        }
    };

    STAGE(0, 0); STAGE(32, 1);                        // steps 0,1
    WAITVM6; BAR(); STAGE(64,  2); COMPUTE(0);        // t=0
    WAITVM6; BAR(); STAGE(96,  0); COMPUTE(1);        // t=1
    WAITVM6; BAR(); STAGE(128, 1); COMPUTE(2);        // t=2
    WAITVM6; BAR(); STAGE(160, 2); COMPUTE(0);        // t=3
    WAITVM6; BAR(); STAGE(192, 0); COMPUTE(1);        // t=4
    WAITVM6; BAR(); STAGE(224, 1); COMPUTE(2);        // t=5
    WAITVM6; BAR(); COMPUTE(0);                       // t=6 (step 7 in flight)
    WAITVM0; BAR(); COMPUTE(1);                       // t=7

#pragma unroll
    for (int i = 0; i < 8; ++i) {
        const int co_b = wr * 128 + i * 16 + l16 * 4;
        float sc[4], sh[4];
#pragma unroll
        for (int r = 0; r < 4; ++r) {
            sc[r] = g[co_b + r] * rsqrtf(vv[co_b + r] + EPS);
            sh[r] = bb[co_b + r] - mm_[co_b + r] * sc[r];
        }
#pragma unroll
        for (int jj = 0; jj < 4; ++jj) {
            const int n = n0 + wc * 64 + jj * 16 + l15;
            u16x4 o;
#pragma unroll
            for (int r = 0; r < 4; ++r) {
                const float v = fmaxf(fmaf(acc[i][jj][r], sc[r], sh[r]), 0.f);
                __hip_bfloat16 hv = __float2bfloat16(v);
                o[r] = *reinterpret_cast<unsigned short*>(&hv);
            }
            *reinterpret_cast<u16x4*>(&h[(size_t)n * 256 + co_b]) = o;
        }
    }
}

// ---------------- head layer 2: 1x1 conv (256 -> 10) + bias, NCHW out --------
__global__ __launch_bounds__(256) void head2(
    const __hip_bfloat16* __restrict__ h,  // [N][256]
    const float* __restrict__ w2,          // [10][256]
    const float* __restrict__ b2,          // [10]
    float* __restrict__ out)               // [B][10][25][25]
{
    const int py = blockIdx.x, b = blockIdx.y;
    __shared__ __hip_bfloat16 lh[25][258];
    __shared__ float lw[10][256];

    const __hip_bfloat16* hp = h + ((size_t)b * 625 + (size_t)py * 25) * 256;
    for (int i = threadIdx.x; i < 25 * 256; i += 256) {
        int px = i >> 8, c = i & 255;
        lh[px][c] = hp[i];
    }
    for (int i = threadIdx.x; i < 10 * 256; i += 256)
        lw[i >> 8][i & 255] = w2[i];
    __syncthreads();

    if (threadIdx.x < 250) {
        const int o = threadIdx.x / 25, px = threadIdx.x % 25;
        float a = b2[o];
        for (int c = 0; c < 256; ++c)
            a = fmaf(__bfloat162float(lh[px][c]), lw[o][c], a);
        out[(((size_t)b * 10 + o) * 25 + py) * 25 + px] = a;
    }
}

extern "C" void kernel_launch(void* const* d_in, const int* in_sizes, int n_in,
                              void* d_out, int out_size, void* d_ws, size_t ws_size,
                              hipStream_t stream) {
    const float* kernel = (const float*)d_in[0];   // [128,256,7,7]
    const float* search = (const float*)d_in[1];   // [128,256,31,31]
    const float* w_ck   = (const float*)d_in[2];
    const float* g1 = (const float*)d_in[3];
    const float* b1 = (const float*)d_in[4];
    const float* m1 = (const float*)d_in[5];
    const float* v1 = (const float*)d_in[6];
    const float* w_cs   = (const float*)d_in[7];
    const float* g2 = (const float*)d_in[8];
    const float* b2 = (const float*)d_in[9];
    const float* m2 = (const float*)d_in[10];
    const float* v2 = (const float*)d_in[11];
    const float* w_h1   = (const float*)d_in[12];
    const float* g3 = (const float*)d_in[13];
    const float* b3 = (const float*)d_in[14];
    const float* m3 = (const float*)d_in[15];
    const float* v3 = (const float*)d_in[16];
    const float* w_h2   = (const float*)d_in[17];
    const float* b_h2   = (const float*)d_in[18];

    float* out = (float*)d_out;

    // ws layout (bf16 elements):
    //  y1    [128*25*256]  NHWC @ 0         (819200)
    //  y2    [128*841*256] NHWC @ 819200    (27557888) -> 28377088
    //  wt_ck [256*9*256]        @ 28377088  (589824)   -> 28966912
    //  wt_cs [256*9*256]        @ 28966912  (589824)   -> 29556736
    //  wh1   [256*256]          @ 29556736  (65536)    -> 29622272
    //  xt_k  [128*49*256]       @ 29622272  (1605632)  -> 31227904
    //  xt_s  [128*961*256]      @ 31227904  (31490048) -> 62717952 (125.4 MB)
    //  feat  [80000*256]   NHWC @ 29622272  (reuses xt region after convs)
    //  h     [80000*256]   NHWC @ 819200    (reuses y2 after xcorr)
    __hip_bfloat16* ws = (__hip_bfloat16*)d_ws;
    __hip_bfloat16* y1    = ws;
    __hip_bfloat16* y2    = ws + (size_t)819200;
    __hip_bfloat16* wt_ck = ws + (size_t)28377088;
    __hip_bfloat16* wt_cs = ws + (size_t)28966912;
    __hip_bfloat16* wh1   = ws + (size_t)29556736;
    __hip_bfloat16* xt_k  = ws + (size_t)29622272;
    __hip_bfloat16* xt_s  = ws + (size_t)31227904;
    __hip_bfloat16* feat  = ws + (size_t)29622272;
    __hip_bfloat16* h     = ws + (size_t)819200;

    (void)in_sizes; (void)n_in; (void)out_size; (void)ws_size;

    // pre-passes
    wt_transpose_bf16<<<256, 256, 0, stream>>>(w_ck, wt_ck);
    wt_transpose_bf16<<<256, 256, 0, stream>>>(w_cs, wt_cs);
    f32_to_bf16<<<256, 256, 0, stream>>>(w_h1, wh1, 65536);
    nchw_to_nhwc_bf16<<<dim3(2, 8, 128), 256, 0, stream>>>(kernel, xt_k, 49);
    nchw_to_nhwc_bf16<<<dim3(31, 8, 128), 256, 0, stream>>>(search, xt_s, 961);

    // convs (MFMA implicit GEMM, 256xM full), NHWC outputs
    conv3x3_mfma<7, 7><<<25, 256, 0, stream>>>(
        xt_k, wt_ck, g1, b1, m1, v1, y1);        // N = 3200 = 25*128
    conv3x3_mfma<31, 31><<<841, 256, 0, stream>>>(
        xt_s, wt_cs, g2, b2, m2, v2, y2);        // N = 107648 = 841*128

    // depthwise xcorr -> feat NHWC
    xcorr_dw_nhwc<<<dim3(25, 128), 256, 0, stream>>>(y2, y1, feat);

    // head
    head1_mfma<<<625, 256, 0, stream>>>(feat, wh1, g3, b3, m3, v3, h);
    head2<<<dim3(25, 128), 256, 0, stream>>>(h, w_h2, b_h2, out);
}

// Round 8
// 356.820 us; speedup vs baseline: 1.0885x; 1.0400x over previous
//
#include <hip/hip_runtime.h>
#include <hip/hip_bf16.h>

#define EPS 1e-5f

typedef __attribute__((ext_vector_type(8))) short bf16x8;
typedef __attribute__((ext_vector_type(4))) float f32x4;
typedef __attribute__((ext_vector_type(4))) unsigned short u16x4;
typedef __attribute__((ext_vector_type(8))) unsigned short u16x8;

#define WAITVM8 asm volatile("s_waitcnt vmcnt(8)" ::: "memory")
#define WAITVM6 asm volatile("s_waitcnt vmcnt(6)" ::: "memory")
#define WAITVM4 asm volatile("s_waitcnt vmcnt(4)" ::: "memory")
#define WAITVM0 asm volatile("s_waitcnt vmcnt(0)" ::: "memory")
#define BAR()   __builtin_amdgcn_s_barrier()

// ---- async global->LDS, 16B per lane, linear dest (wave-uniform base + lane*16)
__device__ __forceinline__ void gld_lds16(const void* g, void* l) {
    __builtin_amdgcn_global_load_lds(
        (const __attribute__((address_space(1))) unsigned int*)g,
        (__attribute__((address_space(3))) unsigned int*)l, 16, 0, 0);
}

// ---- phase-pipelined GEMM step macros (shared by conv3x3_mfma8 / head1_mfma8)
// Requires in scope: lA, lB (4 bufs x 8192 elems), aoff, boff, acc[8][4].
#define RD_FRAGS(RA, RB, SEL) do {                                             \
    const int _bse = (SEL) * 8192;                                             \
    _Pragma("unroll") for (int _i = 0; _i < 8; ++_i)                           \
        RA[_i] = *reinterpret_cast<const bf16x8*>(&lA[_bse + aoff + _i * 512]);\
    _Pragma("unroll") for (int _j = 0; _j < 4; ++_j)                           \
        RB[_j] = *reinterpret_cast<const bf16x8*>(&lB[_bse + boff + _j * 512]);\
} while (0)

#define MF_HALF(RA, RB, I0) do {                                               \
    _Pragma("unroll") for (int _i = 0; _i < 4; ++_i) {                         \
        _Pragma("unroll") for (int _j = 0; _j < 4; ++_j)                       \
            acc[(I0) + _i][_j] = __builtin_amdgcn_mfma_f32_16x16x32_bf16(      \
                RA[(I0) + _i], RB[_j], acc[(I0) + _i][_j], 0, 0, 0);           \
    } } while (0)

#define PIPE_STEP(CA, CB, NA, NB, STAGE_STMT, WAIT_STMT, RSEL, DOREAD) do {    \
    BAR();                                                                     \
    STAGE_STMT;                                                                \
    __builtin_amdgcn_s_setprio(1); MF_HALF(CA, CB, 0);                         \
    __builtin_amdgcn_s_setprio(0);                                             \
    WAIT_STMT;                                                                 \
    BAR();                                                                     \
    if (DOREAD) RD_FRAGS(NA, NB, RSEL);                                        \
    __builtin_amdgcn_s_setprio(1); MF_HALF(CA, CB, 4);                         \
    __builtin_amdgcn_s_setprio(0);                                             \
} while (0)

// ---------------- pre-pass: weights [256][256][3][3] f32 -> [256][9][256] bf16
__global__ __launch_bounds__(256) void wt_transpose_bf16(
    const float* __restrict__ w, __hip_bfloat16* __restrict__ wt)
{
    const int co = blockIdx.x;
    const int ci = threadIdx.x;
    const float* wp = w + (size_t)co * 2304 + (size_t)ci * 9;
    __hip_bfloat16* wo = wt + (size_t)co * 2304 + ci;
#pragma unroll
    for (int j = 0; j < 9; ++j)
        wo[(size_t)j * 256] = __float2bfloat16(wp[j]);
}

// ---------------- pre-pass: f32 -> bf16 elementwise (for w_h1)
__global__ __launch_bounds__(256) void f32_to_bf16(
    const float* __restrict__ x, __hip_bfloat16* __restrict__ y, int n)
{
    int i = blockIdx.x * 256 + threadIdx.x;
    if (i < n) y[i] = __float2bfloat16(x[i]);
}

// ---------------- pre-pass v2: x [B][256][P] f32 -> xt [B][P][256] bf16
// tile 256ch x 32px; both sides coalesced; 16B stores.
__global__ __launch_bounds__(256) void nchw_to_nhwc_v2(
    const float* __restrict__ x, __hip_bfloat16* __restrict__ xt, int P)
{
    const int b  = blockIdx.y;
    const int p0 = blockIdx.x * 32;
    __shared__ float t[256][33];
    const float* xb = x + (size_t)b * 256 * P;
    const int pl = threadIdx.x & 31, cg = threadIdx.x >> 5;
#pragma unroll
    for (int it = 0; it < 32; ++it) {
        int c = cg + it * 8, p = p0 + pl;
        t[c][pl] = (p < P) ? xb[(size_t)c * P + p] : 0.f;
    }
    __syncthreads();
    const int p = threadIdx.x >> 3, l8 = threadIdx.x & 7;
    if (p0 + p < P) {
        __hip_bfloat16* xo = xt + ((size_t)b * P + p0 + p) * 256;
#pragma unroll
        for (int j = 0; j < 4; ++j) {
            const int c0 = j * 64 + l8 * 8;
            u16x8 o;
#pragma unroll
            for (int r = 0; r < 8; ++r) {
                __hip_bfloat16 hv = __float2bfloat16(t[c0 + r][p]);
                o[r] = *reinterpret_cast<unsigned short*>(&hv);
            }
            *reinterpret_cast<u16x8*>(&xo[c0]) = o;
        }
    }
}

// ---------------- conv3x3 search-branch: 8-wave phase-pipelined implicit GEMM
// M=256 (full), N-tile=256 px, K=2304 (72 steps of BK=32). 512 thr = 8 waves
// (2M x 4N), per-wave 128x64. 4 LDS bufs (128 KB), depth-3 staging, counted
// vmcnt(8), 2 barriers/step, next-step frags read during current MFMA cluster.
template<int HIN, int WIN, int NTOT>
__global__ __launch_bounds__(512, 2) void conv3x3_mfma8(
    const __hip_bfloat16* __restrict__ xt,  // [B][HIN][WIN][256]
    const __hip_bfloat16* __restrict__ wt,  // [256][9][256]
    const float* __restrict__ g, const float* __restrict__ bb,
    const float* __restrict__ mm_, const float* __restrict__ vv,
    __hip_bfloat16* __restrict__ y)         // NHWC: [NTOT][256]
{
    constexpr int HOUT = HIN - 2, WOUT = WIN - 2, POUT = HOUT * WOUT;
    const int n0  = blockIdx.x * 256;
    const int tid = threadIdx.x;
    const int wid = tid >> 6, lane = tid & 63;
    const int wr = wid >> 2, wc = wid & 3;

    __shared__ __align__(16) __hip_bfloat16 lA[4 * 8192];  // 4 bufs of [256][32]
    __shared__ __align__(16) __hip_bfloat16 lB[4 * 8192];

    const int arow = tid >> 2;                       // 0..127
    const int seg  = (tid & 3) ^ ((tid >> 3) & 3);   // inverse slot-swizzle

    const size_t wbase0 = (size_t)arow * 2304 + seg * 8;
    const size_t wbase1 = (size_t)(arow + 128) * 2304 + seg * 8;

    int nr0 = n0 + arow;       if (nr0 > NTOT - 1) nr0 = NTOT - 1;
    int nr1 = n0 + arow + 128; if (nr1 > NTOT - 1) nr1 = NTOT - 1;
    int b0 = nr0 / POUT, p0 = nr0 % POUT, oy0 = p0 / WOUT, ox0 = p0 % WOUT;
    int b1 = nr1 / POUT, p1 = nr1 % POUT, oy1 = p1 / WOUT, ox1 = p1 % WOUT;
    const size_t xbase0 = (((size_t)b0 * HIN + oy0) * WIN + ox0) * 256 + seg * 8;
    const size_t xbase1 = (((size_t)b1 * HIN + oy1) * WIN + ox1) * 256 + seg * 8;

    // 4 gld_lds16 per wave per stage
    auto stage = [&](int c0, int j, int sel) {
        char* a0 = (char*)lA + sel * 16384 + wid * 1024;
        char* b0p = (char*)lB + sel * 16384 + wid * 1024;
        const int woff = j * 256 + c0;
        gld_lds16(wt + wbase0 + woff, a0);
        gld_lds16(wt + wbase1 + woff, a0 + 8192);
        const int xoff = ((j / 3) * WIN + (j % 3)) * 256 + c0;
        gld_lds16(xt + xbase0 + xoff, b0p);
        gld_lds16(xt + xbase1 + xoff, b0p + 8192);
    };

    f32x4 acc[8][4];
#pragma unroll
    for (int i = 0; i < 8; ++i)
#pragma unroll
        for (int j = 0; j < 4; ++j)
            acc[i][j] = f32x4{0.f, 0.f, 0.f, 0.f};

    const int l15 = lane & 15, l16 = lane >> 4;
    const int slot = l16 ^ ((l15 >> 1) & 3);
    const int aoff = (wr * 128 + l15) * 32 + slot * 8;
    const int boff = (wc * 64  + l15) * 32 + slot * 8;

    bf16x8 pA[8], pB[4], qA[8], qB[4];

    // prologue: stage 0,1,2 (12 gld in flight); read frags(0) -> P
    stage(0, 0, 0); stage(0, 1, 1); stage(0, 2, 2);
    int js = 3, c0s = 0, ss = 3, rs = 1;
    WAITVM8; BAR();
    RD_FRAGS(pA, pB, 0);

    // main loop: steps t=0..67 (pairs)
    for (int tt = 0; tt < 34; ++tt) {
        PIPE_STEP(pA, pB, qA, qB, stage(c0s, js, ss & 3), WAITVM8, rs & 3, true);
        ++js; if (js == 9) { js = 0; c0s += 32; } ++ss; ++rs;
        PIPE_STEP(qA, qB, pA, pB, stage(c0s, js, ss & 3), WAITVM8, rs & 3, true);
        ++js; if (js == 9) { js = 0; c0s += 32; } ++ss; ++rs;
    }
    // tail: t=68 (stages 71), 69, 70, 71
    PIPE_STEP(pA, pB, qA, qB, stage(c0s, js, ss & 3), WAITVM8, rs & 3, true); ++rs;
    PIPE_STEP(qA, qB, pA, pB, (void)0, WAITVM4, rs & 3, true); ++rs;
    PIPE_STEP(pA, pB, qA, qB, (void)0, WAITVM0, rs & 3, true);
    PIPE_STEP(qA, qB, pA, pB, (void)0, (void)0, 0, false);

    // epilogue: co = wr*128 + i*16 + l16*4 + r; n = n0 + wc*64 + jj*16 + l15
#pragma unroll
    for (int i = 0; i < 8; ++i) {
        const int co_b = wr * 128 + i * 16 + l16 * 4;
        float sc[4], sh[4];
#pragma unroll
        for (int r = 0; r < 4; ++r) {
            sc[r] = g[co_b + r] * rsqrtf(vv[co_b + r] + EPS);
            sh[r] = bb[co_b + r] - mm_[co_b + r] * sc[r];
        }
#pragma unroll
        for (int jj = 0; jj < 4; ++jj) {
            const int n = n0 + wc * 64 + jj * 16 + l15;
            if (n < NTOT) {
                u16x4 o;
#pragma unroll
                for (int r = 0; r < 4; ++r) {
                    const float v = fmaxf(fmaf(acc[i][jj][r], sc[r], sh[r]), 0.f);
                    __hip_bfloat16 hv = __float2bfloat16(v);
                    o[r] = *reinterpret_cast<unsigned short*>(&hv);
                }
                *reinterpret_cast<u16x4*>(&y[(size_t)n * 256 + co_b]) = o;
            }
        }
    }
}

// ---------------- conv3x3 kernel-branch: split-K partial (round-7 structure)
// Block: 256x128 tile, 4 waves, K-chunk = 64 ci x 9 taps = 18 steps of BK=32.
// Output f32 partials [4][3200][256].
__global__ __launch_bounds__(256, 2) void conv3x3_partial(
    const __hip_bfloat16* __restrict__ xt,  // [B][7][7][256]
    const __hip_bfloat16* __restrict__ wt,  // [256][9][256]
    float* __restrict__ part)               // [4][3200][256]
{
    constexpr int HIN = 7, WIN = 7, POUT = 25;
    const int n0  = blockIdx.x * 128;
    const int kc0 = blockIdx.y * 64;
    const int kidx = blockIdx.y;
    const int tid = threadIdx.x;
    const int wid = tid >> 6, lane = tid & 63;
    const int wr = wid >> 1, wc = wid & 1;

    __shared__ __align__(16) __hip_bfloat16 sA[3 * 8192];
    __shared__ __align__(16) __hip_bfloat16 sB[3 * 4096];

    const int srow = wid * 16 + (lane >> 2);
    const int seg  = (lane & 3) ^ ((lane >> 3) & 3);

    const size_t wbase = (size_t)srow * 2304 + seg * 8;
    int nr0 = n0 + srow;
    int b0 = nr0 / POUT, p0 = nr0 % POUT, oy0 = p0 / 5, ox0 = p0 % 5;
    const size_t xbase0 = (((size_t)b0 * HIN + oy0) * WIN + ox0) * 256 + seg * 8;
    int nr1 = nr0 + 64;
    int b1 = nr1 / POUT, p1 = nr1 % POUT, oy1 = p1 / 5, ox1 = p1 % 5;
    const size_t xbase1 = (((size_t)b1 * HIN + oy1) * WIN + ox1) * 256 + seg * 8;

    auto stage = [&](int c0, int j, int sel) {
        char* a0 = (char*)sA + sel * 16384 + wid * 1024;
        char* b0p = (char*)sB + sel * 8192 + wid * 1024;
        const int woff = j * 256 + c0;
        gld_lds16(wt + wbase + woff,              a0);
        gld_lds16(wt + wbase + 64 * 2304 + woff,  a0 + 4096);
        gld_lds16(wt + wbase + 128 * 2304 + woff, a0 + 8192);
        gld_lds16(wt + wbase + 192 * 2304 + woff, a0 + 12288);
        const int xoff = ((j / 3) * WIN + (j % 3)) * 256 + c0;
        gld_lds16(xt + xbase0 + xoff, b0p);
        gld_lds16(xt + xbase1 + xoff, b0p + 4096);
    };

    f32x4 acc[8][4];
#pragma unroll
    for (int i = 0; i < 8; ++i)
#pragma unroll
        for (int j = 0; j < 4; ++j)
            acc[i][j] = f32x4{0.f, 0.f, 0.f, 0.f};

    const int l15 = lane & 15, l16 = lane >> 4;
    const int slot = l16 ^ ((l15 >> 1) & 3);
    const int aoffp = (wr * 128 + l15) * 32 + slot * 8;
    const int boffp = (wc * 64  + l15) * 32 + slot * 8;

    auto compute = [&](int sel) {
        const int ab = sel * 8192, bb_ = sel * 4096;
        bf16x8 b[4];
#pragma unroll
        for (int j = 0; j < 4; ++j)
            b[j] = *reinterpret_cast<const bf16x8*>(&sB[bb_ + boffp + j * 512]);
#pragma unroll
        for (int i = 0; i < 8; ++i) {
            bf16x8 a = *reinterpret_cast<const bf16x8*>(&sA[ab + aoffp + i * 512]);
#pragma unroll
            for (int j = 0; j < 4; ++j)
                acc[i][j] = __builtin_amdgcn_mfma_f32_16x16x32_bf16(
                    a, b[j], acc[i][j], 0, 0, 0);
        }
    };

    // 18 steps: prologue stages 0,1; loop t=0..15 stages t+2; tail 16,17
    stage(kc0, 0, 0); stage(kc0, 1, 1);
    int js = 2, c0s = kc0;
    for (int t = 0; t < 16; ++t) {
        WAITVM6; BAR();
        stage(c0s, js, (t + 2) % 3);
        ++js; if (js == 9) { js = 0; c0s += 32; }
        compute(t % 3);
    }
    WAITVM6; BAR(); compute(16 % 3);
    WAITVM0; BAR(); compute(17 % 3);

#pragma unroll
    for (int i = 0; i < 8; ++i) {
        const int co_b = wr * 128 + i * 16 + l16 * 4;
#pragma unroll
        for (int jj = 0; jj < 4; ++jj) {
            const int n = n0 + wc * 64 + jj * 16 + l15;
            f32x4 o = acc[i][jj];
            *reinterpret_cast<f32x4*>(
                &part[((size_t)kidx * 3200 + n) * 256 + co_b]) = o;
        }
    }
}

// ---------------- reduce split-K partials + BN + ReLU -> y1 bf16
__global__ __launch_bounds__(256) void reduce_bn_relu(
    const float* __restrict__ part,  // [4][3200][256]
    const float* __restrict__ g, const float* __restrict__ bb,
    const float* __restrict__ mm_, const float* __restrict__ vv,
    __hip_bfloat16* __restrict__ y1) // [3200][256]
{
    const int n = blockIdx.x, co = threadIdx.x;
    float s = part[(size_t)n * 256 + co]
            + part[((size_t)3200 + n) * 256 + co]
            + part[((size_t)6400 + n) * 256 + co]
            + part[((size_t)9600 + n) * 256 + co];
    const float sc = g[co] * rsqrtf(vv[co] + EPS);
    const float sh = bb[co] - mm_[co] * sc;
    y1[(size_t)n * 256 + co] = __float2bfloat16(fmaxf(fmaf(s, sc, sh), 0.f));
}

// ---------------- depthwise xcorr 5x5, NHWC, bf16x2 vectorized ----------------
__global__ __launch_bounds__(128) void xcorr_dw_nhwc2(
    const __hip_bfloat16* __restrict__ s,  // [B][841][256]
    const __hip_bfloat16* __restrict__ k,  // [B][25][256]
    __hip_bfloat16* __restrict__ f)        // [B][625][256]
{
    const int py = blockIdx.x, b = blockIdx.y, c2 = threadIdx.x;  // ch pair
    const ushort2* sp = reinterpret_cast<const ushort2*>(s + (size_t)b * 841 * 256) + c2;
    const ushort2* kp = reinterpret_cast<const ushort2*>(k + (size_t)b * 25 * 256) + c2;

    float a0[25], a1[25];
#pragma unroll
    for (int i = 0; i < 25; ++i) { a0[i] = 0.f; a1[i] = 0.f; }

    for (int ky = 0; ky < 5; ++ky) {
        const ushort2* srp = sp + (size_t)(py + ky) * 29 * 128;
        float s0[29], s1[29];
#pragma unroll
        for (int rx = 0; rx < 29; ++rx) {
            ushort2 u = srp[(size_t)rx * 128];
            unsigned int w0 = (unsigned int)u.x << 16, w1 = (unsigned int)u.y << 16;
            s0[rx] = *reinterpret_cast<float*>(&w0);
            s1[rx] = *reinterpret_cast<float*>(&w1);
        }
#pragma unroll
        for (int kx = 0; kx < 5; ++kx) {
            ushort2 u = kp[(size_t)(ky * 5 + kx) * 128];
            unsigned int w0 = (unsigned int)u.x << 16, w1 = (unsigned int)u.y << 16;
            const float k0 = *reinterpret_cast<float*>(&w0);
            const float k1 = *reinterpret_cast<float*>(&w1);
#pragma unroll
            for (int px = 0; px < 25; ++px) {
                a0[px] = fmaf(s0[px + kx], k0, a0[px]);
                a1[px] = fmaf(s1[px + kx], k1, a1[px]);
            }
        }
    }

    ushort2* fp = reinterpret_cast<ushort2*>(f + ((size_t)b * 625 + (size_t)py * 25) * 256) + c2;
#pragma unroll
    for (int px = 0; px < 25; ++px) {
        __hip_bfloat16 h0 = __float2bfloat16(a0[px]);
        __hip_bfloat16 h1 = __float2bfloat16(a1[px]);
        ushort2 o;
        o.x = *reinterpret_cast<unsigned short*>(&h0);
        o.y = *reinterpret_cast<unsigned short*>(&h1);
        fp[(size_t)px * 128] = o;
    }
}

// ---------------- head layer 1: 1x1 conv, 8-wave phase-pipelined -------------
// GEMM M=256, N=80000 (313 tiles of 256, tail-guarded), K=256 (8 steps).
__global__ __launch_bounds__(512, 2) void head1_mfma8(
    const __hip_bfloat16* __restrict__ f,   // [N][256]
    const __hip_bfloat16* __restrict__ w1,  // [256][256] bf16
    const float* __restrict__ g, const float* __restrict__ bb,
    const float* __restrict__ mm_, const float* __restrict__ vv,
    __hip_bfloat16* __restrict__ h)         // [N][256]
{
    constexpr int NTOT = 80000;
    const int n0  = blockIdx.x * 256;
    const int tid = threadIdx.x;
    const int wid = tid >> 6, lane = tid & 63;
    const int wr = wid >> 2, wc = wid & 3;

    __shared__ __align__(16) __hip_bfloat16 lA[4 * 8192];
    __shared__ __align__(16) __hip_bfloat16 lB[4 * 8192];

    const int arow = tid >> 2;
    const int seg  = (tid & 3) ^ ((tid >> 3) & 3);

    const size_t wbase0 = (size_t)arow * 256 + seg * 8;
    const size_t wbase1 = (size_t)(arow + 128) * 256 + seg * 8;
    int nr0 = n0 + arow;       if (nr0 > NTOT - 1) nr0 = NTOT - 1;
    int nr1 = n0 + arow + 128; if (nr1 > NTOT - 1) nr1 = NTOT - 1;
    const size_t xbase0 = (size_t)nr0 * 256 + seg * 8;
    const size_t xbase1 = (size_t)nr1 * 256 + seg * 8;

    auto stage = [&](int c0, int sel) {
        char* a0 = (char*)lA + sel * 16384 + wid * 1024;
        char* b0p = (char*)lB + sel * 16384 + wid * 1024;
        gld_lds16(w1 + wbase0 + c0, a0);
        gld_lds16(w1 + wbase1 + c0, a0 + 8192);
        gld_lds16(f + xbase0 + c0, b0p);
        gld_lds16(f + xbase1 + c0, b0p + 8192);
    };

    f32x4 acc[8][4];
#pragma unroll
    for (int i = 0; i < 8; ++i)
#pragma unroll
        for (int j = 0; j < 4; ++j)
            acc[i][j] = f32x4{0.f, 0.f, 0.f, 0.f};

    const int l15 = lane & 15, l16 = lane >> 4;
    const int slot = l16 ^ ((l15 >> 1) & 3);
    const int aoff = (wr * 128 + l15) * 32 + slot * 8;
    const int boff = (wc * 64  + l15) * 32 + slot * 8;

    bf16x8 pA[8], pB[4], qA[8], qB[4];

    stage(0, 0); stage(32, 1); stage(64, 2);
    WAITVM8; BAR();
    RD_FRAGS(pA, pB, 0);

    PIPE_STEP(pA, pB, qA, qB, stage(96, 3),  WAITVM8, 1, true);   // t=0
    PIPE_STEP(qA, qB, pA, pB, stage(128, 0), WAITVM8, 2, true);   // t=1
    PIPE_STEP(pA, pB, qA, qB, stage(160, 1), WAITVM8, 3, true);   // t=2
    PIPE_STEP(qA, qB, pA, pB, stage(192, 2), WAITVM8, 0, true);   // t=3
    PIPE_STEP(pA, pB, qA, qB, stage(224, 3), WAITVM8, 1, true);   // t=4
    PIPE_STEP(qA, qB, pA, pB, (void)0,       WAITVM4, 2, true);   // t=5
    PIPE_STEP(pA, pB, qA, qB, (void)0,       WAITVM0, 3, true);   // t=6
    PIPE_STEP(qA, qB, pA, pB, (void)0,       (void)0, 0, false);  // t=7

#pragma unroll
    for (int i = 0; i < 8; ++i) {
        const int co_b = wr * 128 + i * 16 + l16 * 4;
        float sc[4], sh[4];
#pragma unroll
        for (int r = 0; r < 4; ++r) {
            sc[r] = g[co_b + r] * rsqrtf(vv[co_b + r] + EPS);
            sh[r] = bb[co_b + r] - mm_[co_b + r] * sc[r];
        }
#pragma unroll
        for (int jj = 0; jj < 4; ++jj) {
            const int n = n0 + wc * 64 + jj * 16 + l15;
            if (n < NTOT) {
                u16x4 o;
#pragma unroll
                for (int r = 0; r < 4; ++r) {
                    const float v = fmaxf(fmaf(acc[i][jj][r], sc[r], sh[r]), 0.f);
                    __hip_bfloat16 hv = __float2bfloat16(v);
                    o[r] = *reinterpret_cast<unsigned short*>(&hv);
                }
                *reinterpret_cast<u16x4*>(&h[(size_t)n * 256 + co_b]) = o;
            }
        }
    }
}

// ---------------- head layer 2: 1x1 conv (256 -> 10) + bias, NCHW out --------
__global__ __launch_bounds__(256) void head2(
    const __hip_bfloat16* __restrict__ h,  // [N][256]
    const float* __restrict__ w2,          // [10][256]
    const float* __restrict__ b2,          // [10]
    float* __restrict__ out)               // [B][10][25][25]
{
    const int py = blockIdx.x, b = blockIdx.y;
    __shared__ __hip_bfloat16 lh[25][258];
    __shared__ float lw[10][256];

    const __hip_bfloat16* hp = h + ((size_t)b * 625 + (size_t)py * 25) * 256;
    for (int i = threadIdx.x; i < 25 * 256; i += 256) {
        int px = i >> 8, c = i & 255;
        lh[px][c] = hp[i];
    }
    for (int i = threadIdx.x; i < 10 * 256; i += 256)
        lw[i >> 8][i & 255] = w2[i];
    __syncthreads();

    if (threadIdx.x < 250) {
        const int o = threadIdx.x / 25, px = threadIdx.x % 25;
        float a = b2[o];
        for (int c = 0; c < 256; ++c)
            a = fmaf(__bfloat162float(lh[px][c]), lw[o][c], a);
        out[(((size_t)b * 10 + o) * 25 + py) * 25 + px] = a;
    }
}

extern "C" void kernel_launch(void* const* d_in, const int* in_sizes, int n_in,
                              void* d_out, int out_size, void* d_ws, size_t ws_size,
                              hipStream_t stream) {
    const float* kernel = (const float*)d_in[0];   // [128,256,7,7]
    const float* search = (const float*)d_in[1];   // [128,256,31,31]
    const float* w_ck   = (const float*)d_in[2];
    const float* g1 = (const float*)d_in[3];
    const float* b1 = (const float*)d_in[4];
    const float* m1 = (const float*)d_in[5];
    const float* v1 = (const float*)d_in[6];
    const float* w_cs   = (const float*)d_in[7];
    const float* g2 = (const float*)d_in[8];
    const float* b2 = (const float*)d_in[9];
    const float* m2 = (const float*)d_in[10];
    const float* v2 = (const float*)d_in[11];
    const float* w_h1   = (const float*)d_in[12];
    const float* g3 = (const float*)d_in[13];
    const float* b3 = (const float*)d_in[14];
    const float* m3 = (const float*)d_in[15];
    const float* v3 = (const float*)d_in[16];
    const float* w_h2   = (const float*)d_in[17];
    const float* b_h2   = (const float*)d_in[18];

    float* out = (float*)d_out;

    // ws layout (bf16 elements):
    //  y1    [3200*256]    NHWC @ 0         (819200)
    //  y2    [107648*256]  NHWC @ 819200    (27557888) -> 28377088
    //    (partials [4][3200][256] f32 alias y2's region before conv_search;
    //     h [80000][256] bf16 aliases y2 after xcorr)
    //  wt_ck @ 28377088 (589824), wt_cs @ 28966912 (589824), wh1 @ 29556736 (65536)
    //  xt_k  @ 29622272 (1605632), xt_s @ 31227904 (31490048) -> 62717952
    //  feat  [80000*256] @ 29622272 (reuses xt after convs)
    __hip_bfloat16* ws = (__hip_bfloat16*)d_ws;
    __hip_bfloat16* y1    = ws;
    __hip_bfloat16* y2    = ws + (size_t)819200;
    float*          part  = (float*)(ws + (size_t)819200);
    __hip_bfloat16* wt_ck = ws + (size_t)28377088;
    __hip_bfloat16* wt_cs = ws + (size_t)28966912;
    __hip_bfloat16* wh1   = ws + (size_t)29556736;
    __hip_bfloat16* xt_k  = ws + (size_t)29622272;
    __hip_bfloat16* xt_s  = ws + (size_t)31227904;
    __hip_bfloat16* feat  = ws + (size_t)29622272;
    __hip_bfloat16* h     = ws + (size_t)819200;

    (void)in_sizes; (void)n_in; (void)out_size; (void)ws_size;

    // pre-passes
    wt_transpose_bf16<<<256, 256, 0, stream>>>(w_ck, wt_ck);
    wt_transpose_bf16<<<256, 256, 0, stream>>>(w_cs, wt_cs);
    f32_to_bf16<<<256, 256, 0, stream>>>(w_h1, wh1, 65536);
    nchw_to_nhwc_v2<<<dim3(2, 128), 256, 0, stream>>>(kernel, xt_k, 49);
    nchw_to_nhwc_v2<<<dim3(31, 128), 256, 0, stream>>>(search, xt_s, 961);

    // kernel branch: split-K x4 partials (into y2 region) + reduce -> y1
    conv3x3_partial<<<dim3(25, 4), 256, 0, stream>>>(xt_k, wt_ck, part);
    reduce_bn_relu<<<3200, 256, 0, stream>>>(part, g1, b1, m1, v1, y1);

    // search branch: phase-pipelined implicit GEMM -> y2 (N=107648, 421 tiles)
    conv3x3_mfma8<31, 31, 107648><<<421, 512, 0, stream>>>(
        xt_s, wt_cs, g2, b2, m2, v2, y2);

    // depthwise xcorr -> feat NHWC
    xcorr_dw_nhwc2<<<dim3(25, 128), 128, 0, stream>>>(y2, y1, feat);

    // head
    head1_mfma8<<<313, 512, 0, stream>>>(feat, wh1, g3, b3, m3, v3, h);
    head2<<<dim3(25, 128), 256, 0, stream>>>(h, w_h2, b_h2, out);
}

// Round 9
// 350.193 us; speedup vs baseline: 1.1091x; 1.0189x over previous
//
#include <hip/hip_runtime.h>
#include <hip/hip_bf16.h>

#define EPS 1e-5f

typedef __attribute__((ext_vector_type(8))) short bf16x8;
typedef __attribute__((ext_vector_type(4))) float f32x4;
typedef __attribute__((ext_vector_type(4))) unsigned short u16x4;
typedef __attribute__((ext_vector_type(8))) unsigned short u16x8;

#define WAITVM8 asm volatile("s_waitcnt vmcnt(8)" ::: "memory")
#define WAITVM6 asm volatile("s_waitcnt vmcnt(6)" ::: "memory")
#define WAITVM4 asm volatile("s_waitcnt vmcnt(4)" ::: "memory")
#define WAITVM0 asm volatile("s_waitcnt vmcnt(0)" ::: "memory")
#define BAR()   __builtin_amdgcn_s_barrier()

// ---- async global->LDS, 16B per lane, linear dest (wave-uniform base + lane*16)
__device__ __forceinline__ void gld_lds16(const void* g, void* l) {
    __builtin_amdgcn_global_load_lds(
        (const __attribute__((address_space(1))) unsigned int*)g,
        (__attribute__((address_space(3))) unsigned int*)l, 16, 0, 0);
}

// ---- GEMM step macros. Requires in scope: lA, lB (4 bufs x 8192 elems),
// aoff, boff, acc[8][4]. Frag sets: {A0[4], A4[4], B[4]} per step parity.
#define RD8(RA, RB, SEL) do {                                                  \
    const int _b = (SEL) * 8192;                                               \
    _Pragma("unroll") for (int _i = 0; _i < 4; ++_i)                           \
        RA[_i] = *reinterpret_cast<const bf16x8*>(&lA[_b + aoff + _i * 512]);  \
    _Pragma("unroll") for (int _j = 0; _j < 4; ++_j)                           \
        RB[_j] = *reinterpret_cast<const bf16x8*>(&lB[_b + boff + _j * 512]);  \
} while (0)

#define RD4(RA4, SEL) do {                                                     \
    const int _b = (SEL) * 8192;                                               \
    _Pragma("unroll") for (int _i = 0; _i < 4; ++_i)                           \
        RA4[_i] = *reinterpret_cast<const bf16x8*>(                            \
            &lA[_b + aoff + (_i + 4) * 512]);                                  \
} while (0)

#define MFQ(RA, RB, I0) do {                                                   \
    _Pragma("unroll") for (int _i = 0; _i < 4; ++_i)                           \
    _Pragma("unroll") for (int _j = 0; _j < 4; ++_j)                           \
        acc[(I0) + _i][_j] = __builtin_amdgcn_mfma_f32_16x16x32_bf16(          \
            RA[_i], RB[_j], acc[(I0) + _i][_j], 0, 0, 0);                      \
} while (0)

// One K-step: 1 barrier, 1 vm-wait, reads split 4 (top) + 8 (mid).
#define STEP(CA0, CA4, CB, NA0, NB, SELT, STAGE_STMT, WAIT_STMT, DORD) do {    \
    RD4(CA4, (SELT));                                                          \
    STAGE_STMT;                                                                \
    __builtin_amdgcn_s_setprio(1); MFQ(CA0, CB, 0);                            \
    __builtin_amdgcn_s_setprio(0);                                             \
    WAIT_STMT;                                                                 \
    BAR();                                                                     \
    if (DORD) RD8(NA0, NB, ((SELT) + 1) & 3);                                  \
    __builtin_amdgcn_s_setprio(1); MFQ(CA4, CB, 4);                            \
    __builtin_amdgcn_s_setprio(0);                                             \
} while (0)

// ---------------- pre-pass: weights [256][256][3][3] f32 -> [256][9][256] bf16
__global__ __launch_bounds__(256) void wt_transpose_bf16(
    const float* __restrict__ w, __hip_bfloat16* __restrict__ wt)
{
    const int co = blockIdx.x;
    const int ci = threadIdx.x;
    const float* wp = w + (size_t)co * 2304 + (size_t)ci * 9;
    __hip_bfloat16* wo = wt + (size_t)co * 2304 + ci;
#pragma unroll
    for (int j = 0; j < 9; ++j)
        wo[(size_t)j * 256] = __float2bfloat16(wp[j]);
}

// ---------------- pre-pass: f32 -> bf16 elementwise (for w_h1)
__global__ __launch_bounds__(256) void f32_to_bf16(
    const float* __restrict__ x, __hip_bfloat16* __restrict__ y, int n)
{
    int i = blockIdx.x * 256 + threadIdx.x;
    if (i < n) y[i] = __float2bfloat16(x[i]);
}

// ---------------- pre-pass v2: x [B][256][P] f32 -> xt [B][P][256] bf16
__global__ __launch_bounds__(256) void nchw_to_nhwc_v2(
    const float* __restrict__ x, __hip_bfloat16* __restrict__ xt, int P)
{
    const int b  = blockIdx.y;
    const int p0 = blockIdx.x * 32;
    __shared__ float t[256][33];
    const float* xb = x + (size_t)b * 256 * P;
    const int pl = threadIdx.x & 31, cg = threadIdx.x >> 5;
#pragma unroll
    for (int it = 0; it < 32; ++it) {
        int c = cg + it * 8, p = p0 + pl;
        t[c][pl] = (p < P) ? xb[(size_t)c * P + p] : 0.f;
    }
    __syncthreads();
    const int p = threadIdx.x >> 3, l8 = threadIdx.x & 7;
    if (p0 + p < P) {
        __hip_bfloat16* xo = xt + ((size_t)b * P + p0 + p) * 256;
#pragma unroll
        for (int j = 0; j < 4; ++j) {
            const int c0 = j * 64 + l8 * 8;
            u16x8 o;
#pragma unroll
            for (int r = 0; r < 8; ++r) {
                __hip_bfloat16 hv = __float2bfloat16(t[c0 + r][p]);
                o[r] = *reinterpret_cast<unsigned short*>(&hv);
            }
            *reinterpret_cast<u16x8*>(&xo[c0]) = o;
        }
    }
}

// ---------------- conv3x3 search-branch: 8-wave pipelined implicit GEMM
// M=256 (full), N-tile=256 px, K=2304 (72 steps of BK=32). 512 thr = 8 waves
// (2M x 4N), per-wave 128x64. 4 LDS bufs (128 KB), depth-3 staging, counted
// vmcnt(8); ONE barrier + ONE vm-wait per step; frag reads split 4+8 so each
// batch has a full 16-MFMA cluster + latency slack before first use.
template<int HIN, int WIN, int NTOT>
__global__ __launch_bounds__(512, 2) void conv3x3_mfma8(
    const __hip_bfloat16* __restrict__ xt,  // [B][HIN][WIN][256]
    const __hip_bfloat16* __restrict__ wt,  // [256][9][256]
    const float* __restrict__ g, const float* __restrict__ bb,
    const float* __restrict__ mm_, const float* __restrict__ vv,
    __hip_bfloat16* __restrict__ y)         // NHWC: [NTOT][256]
{
    constexpr int HOUT = HIN - 2, WOUT = WIN - 2, POUT = HOUT * WOUT;
    const int n0  = blockIdx.x * 256;
    const int tid = threadIdx.x;
    const int wid = tid >> 6, lane = tid & 63;
    const int wr = wid >> 2, wc = wid & 3;

    __shared__ __align__(16) __hip_bfloat16 lA[4 * 8192];  // 4 bufs of [256][32]
    __shared__ __align__(16) __hip_bfloat16 lB[4 * 8192];

    const int arow = tid >> 2;                       // 0..127
    const int seg  = (tid & 3) ^ ((tid >> 3) & 3);   // inverse slot-swizzle

    const size_t wbase0 = (size_t)arow * 2304 + seg * 8;
    const size_t wbase1 = (size_t)(arow + 128) * 2304 + seg * 8;

    int nr0 = n0 + arow;       if (nr0 > NTOT - 1) nr0 = NTOT - 1;
    int nr1 = n0 + arow + 128; if (nr1 > NTOT - 1) nr1 = NTOT - 1;
    int b0 = nr0 / POUT, p0 = nr0 % POUT, oy0 = p0 / WOUT, ox0 = p0 % WOUT;
    int b1 = nr1 / POUT, p1 = nr1 % POUT, oy1 = p1 / WOUT, ox1 = p1 % WOUT;
    const size_t xbase0 = (((size_t)b0 * HIN + oy0) * WIN + ox0) * 256 + seg * 8;
    const size_t xbase1 = (((size_t)b1 * HIN + oy1) * WIN + ox1) * 256 + seg * 8;

    // 4 gld_lds16 per stage
    auto stage = [&](int c0, int j, int sel) {
        char* a0 = (char*)lA + sel * 16384 + wid * 1024;
        char* b0p = (char*)lB + sel * 16384 + wid * 1024;
        const int woff = j * 256 + c0;
        gld_lds16(wt + wbase0 + woff, a0);
        gld_lds16(wt + wbase1 + woff, a0 + 8192);
        const int xoff = ((j / 3) * WIN + (j % 3)) * 256 + c0;
        gld_lds16(xt + xbase0 + xoff, b0p);
        gld_lds16(xt + xbase1 + xoff, b0p + 8192);
    };

    f32x4 acc[8][4];
#pragma unroll
    for (int i = 0; i < 8; ++i)
#pragma unroll
        for (int j = 0; j < 4; ++j)
            acc[i][j] = f32x4{0.f, 0.f, 0.f, 0.f};

    const int l15 = lane & 15, l16 = lane >> 4;
    const int slot = l16 ^ ((l15 >> 1) & 3);
    const int aoff = (wr * 128 + l15) * 32 + slot * 8;
    const int boff = (wc * 64  + l15) * 32 + slot * 8;

    bf16x8 pA0[4], pA4[4], pB[4], qA0[4], qA4[4], qB[4];

    // prologue: stage steps 0,1,2 (12 gld in flight); read frags(0) half-1
    stage(0, 0, 0); stage(0, 1, 1); stage(0, 2, 2);
    int js = 3, c0s = 0;  // stage cursor for step t+3
    WAITVM8; BAR();
    RD8(pA0, pB, 0);

#define ADV do { ++js; if (js == 9) { js = 0; c0s += 32; } } while (0)
    // main loop: t = 0..67
    for (int tt = 0; tt < 17; ++tt) {
        STEP(pA0, pA4, pB, qA0, qB, 0, stage(c0s, js, 3), WAITVM8, true); ADV;
        STEP(qA0, qA4, qB, pA0, pB, 1, stage(c0s, js, 0), WAITVM8, true); ADV;
        STEP(pA0, pA4, pB, qA0, qB, 2, stage(c0s, js, 1), WAITVM8, true); ADV;
        STEP(qA0, qA4, qB, pA0, pB, 3, stage(c0s, js, 2), WAITVM8, true); ADV;
    }
    // tail: t = 68 (stages step 71), 69, 70, 71
    STEP(pA0, pA4, pB, qA0, qB, 0, stage(c0s, js, 3), WAITVM8, true);
    STEP(qA0, qA4, qB, pA0, pB, 1, (void)0,           WAITVM4, true);
    STEP(pA0, pA4, pB, qA0, qB, 2, (void)0,           WAITVM0, true);
    STEP(qA0, qA4, qB, pA0, pB, 3, (void)0,           (void)0, false);
#undef ADV

    // epilogue: co = wr*128 + i*16 + l16*4 + r; n = n0 + wc*64 + jj*16 + l15
#pragma unroll
    for (int i = 0; i < 8; ++i) {
        const int co_b = wr * 128 + i * 16 + l16 * 4;
        float sc[4], sh[4];
#pragma unroll
        for (int r = 0; r < 4; ++r) {
            sc[r] = g[co_b + r] * rsqrtf(vv[co_b + r] + EPS);
            sh[r] = bb[co_b + r] - mm_[co_b + r] * sc[r];
        }
#pragma unroll
        for (int jj = 0; jj < 4; ++jj) {
            const int n = n0 + wc * 64 + jj * 16 + l15;
            if (n < NTOT) {
                u16x4 o;
#pragma unroll
                for (int r = 0; r < 4; ++r) {
                    const float v = fmaxf(fmaf(acc[i][jj][r], sc[r], sh[r]), 0.f);
                    __hip_bfloat16 hv = __float2bfloat16(v);
                    o[r] = *reinterpret_cast<unsigned short*>(&hv);
                }
                *reinterpret_cast<u16x4*>(&y[(size_t)n * 256 + co_b]) = o;
            }
        }
    }
}

// ---------------- conv3x3 kernel-branch: split-K partial ----------------
__global__ __launch_bounds__(256, 2) void conv3x3_partial(
    const __hip_bfloat16* __restrict__ xt,  // [B][7][7][256]
    const __hip_bfloat16* __restrict__ wt,  // [256][9][256]
    float* __restrict__ part)               // [4][3200][256]
{
    constexpr int HIN = 7, WIN = 7, POUT = 25;
    const int n0  = blockIdx.x * 128;
    const int kc0 = blockIdx.y * 64;
    const int kidx = blockIdx.y;
    const int tid = threadIdx.x;
    const int wid = tid >> 6, lane = tid & 63;
    const int wr = wid >> 1, wc = wid & 1;

    __shared__ __align__(16) __hip_bfloat16 sA[3 * 8192];
    __shared__ __align__(16) __hip_bfloat16 sB[3 * 4096];

    const int srow = wid * 16 + (lane >> 2);
    const int seg  = (lane & 3) ^ ((lane >> 3) & 3);

    const size_t wbase = (size_t)srow * 2304 + seg * 8;
    int nr0 = n0 + srow;
    int b0 = nr0 / POUT, p0 = nr0 % POUT, oy0 = p0 / 5, ox0 = p0 % 5;
    const size_t xbase0 = (((size_t)b0 * HIN + oy0) * WIN + ox0) * 256 + seg * 8;
    int nr1 = nr0 + 64;
    int b1 = nr1 / POUT, p1 = nr1 % POUT, oy1 = p1 / 5, ox1 = p1 % 5;
    const size_t xbase1 = (((size_t)b1 * HIN + oy1) * WIN + ox1) * 256 + seg * 8;

    auto stage = [&](int c0, int j, int sel) {
        char* a0 = (char*)sA + sel * 16384 + wid * 1024;
        char* b0p = (char*)sB + sel * 8192 + wid * 1024;
        const int woff = j * 256 + c0;
        gld_lds16(wt + wbase + woff,              a0);
        gld_lds16(wt + wbase + 64 * 2304 + woff,  a0 + 4096);
        gld_lds16(wt + wbase + 128 * 2304 + woff, a0 + 8192);
        gld_lds16(wt + wbase + 192 * 2304 + woff, a0 + 12288);
        const int xoff = ((j / 3) * WIN + (j % 3)) * 256 + c0;
        gld_lds16(xt + xbase0 + xoff, b0p);
        gld_lds16(xt + xbase1 + xoff, b0p + 4096);
    };

    f32x4 acc[8][4];
#pragma unroll
    for (int i = 0; i < 8; ++i)
#pragma unroll
        for (int j = 0; j < 4; ++j)
            acc[i][j] = f32x4{0.f, 0.f, 0.f, 0.f};

    const int l15 = lane & 15, l16 = lane >> 4;
    const int slot = l16 ^ ((l15 >> 1) & 3);
    const int aoffp = (wr * 128 + l15) * 32 + slot * 8;
    const int boffp = (wc * 64  + l15) * 32 + slot * 8;

    auto compute = [&](int sel) {
        const int ab = sel * 8192, bb_ = sel * 4096;
        bf16x8 b[4];
#pragma unroll
        for (int j = 0; j < 4; ++j)
            b[j] = *reinterpret_cast<const bf16x8*>(&sB[bb_ + boffp + j * 512]);
#pragma unroll
        for (int i = 0; i < 8; ++i) {
            bf16x8 a = *reinterpret_cast<const bf16x8*>(&sA[ab + aoffp + i * 512]);
#pragma unroll
            for (int j = 0; j < 4; ++j)
                acc[i][j] = __builtin_amdgcn_mfma_f32_16x16x32_bf16(
                    a, b[j], acc[i][j], 0, 0, 0);
        }
    };

    stage(kc0, 0, 0); stage(kc0, 1, 1);
    int js = 2, c0s = kc0;
    for (int t = 0; t < 16; ++t) {
        WAITVM6; BAR();
        stage(c0s, js, (t + 2) % 3);
        ++js; if (js == 9) { js = 0; c0s += 32; }
        compute(t % 3);
    }
    WAITVM6; BAR(); compute(16 % 3);
    WAITVM0; BAR(); compute(17 % 3);

#pragma unroll
    for (int i = 0; i < 8; ++i) {
        const int co_b = wr * 128 + i * 16 + l16 * 4;
#pragma unroll
        for (int jj = 0; jj < 4; ++jj) {
            const int n = n0 + wc * 64 + jj * 16 + l15;
            f32x4 o = acc[i][jj];
            *reinterpret_cast<f32x4*>(
                &part[((size_t)kidx * 3200 + n) * 256 + co_b]) = o;
        }
    }
}

// ---------------- reduce split-K partials + BN + ReLU -> y1 bf16
__global__ __launch_bounds__(256) void reduce_bn_relu(
    const float* __restrict__ part,  // [4][3200][256]
    const float* __restrict__ g, const float* __restrict__ bb,
    const float* __restrict__ mm_, const float* __restrict__ vv,
    __hip_bfloat16* __restrict__ y1) // [3200][256]
{
    const int n = blockIdx.x, co = threadIdx.x;
    float s = part[(size_t)n * 256 + co]
            + part[((size_t)3200 + n) * 256 + co]
            + part[((size_t)6400 + n) * 256 + co]
            + part[((size_t)9600 + n) * 256 + co];
    const float sc = g[co] * rsqrtf(vv[co] + EPS);
    const float sh = bb[co] - mm_[co] * sc;
    y1[(size_t)n * 256 + co] = __float2bfloat16(fmaxf(fmaf(s, sc, sh), 0.f));
}

// ---------------- depthwise xcorr 5x5, NHWC, bf16x2 vectorized ----------------
__global__ __launch_bounds__(128) void xcorr_dw_nhwc2(
    const __hip_bfloat16* __restrict__ s,  // [B][841][256]
    const __hip_bfloat16* __restrict__ k,  // [B][25][256]
    __hip_bfloat16* __restrict__ f)        // [B][625][256]
{
    const int py = blockIdx.x, b = blockIdx.y, c2 = threadIdx.x;  // ch pair
    const ushort2* sp = reinterpret_cast<const ushort2*>(s + (size_t)b * 841 * 256) + c2;
    const ushort2* kp = reinterpret_cast<const ushort2*>(k + (size_t)b * 25 * 256) + c2;

    float a0[25], a1[25];
#pragma unroll
    for (int i = 0; i < 25; ++i) { a0[i] = 0.f; a1[i] = 0.f; }

    for (int ky = 0; ky < 5; ++ky) {
        const ushort2* srp = sp + (size_t)(py + ky) * 29 * 128;
        float s0[29], s1[29];
#pragma unroll
        for (int rx = 0; rx < 29; ++rx) {
            ushort2 u = srp[(size_t)rx * 128];
            unsigned int w0 = (unsigned int)u.x << 16, w1 = (unsigned int)u.y << 16;
            s0[rx] = *reinterpret_cast<float*>(&w0);
            s1[rx] = *reinterpret_cast<float*>(&w1);
        }
#pragma unroll
        for (int kx = 0; kx < 5; ++kx) {
            ushort2 u = kp[(size_t)(ky * 5 + kx) * 128];
            unsigned int w0 = (unsigned int)u.x << 16, w1 = (unsigned int)u.y << 16;
            const float k0 = *reinterpret_cast<float*>(&w0);
            const float k1 = *reinterpret_cast<float*>(&w1);
#pragma unroll
            for (int px = 0; px < 25; ++px) {
                a0[px] = fmaf(s0[px + kx], k0, a0[px]);
                a1[px] = fmaf(s1[px + kx], k1, a1[px]);
            }
        }
    }

    ushort2* fp = reinterpret_cast<ushort2*>(f + ((size_t)b * 625 + (size_t)py * 25) * 256) + c2;
#pragma unroll
    for (int px = 0; px < 25; ++px) {
        __hip_bfloat16 h0 = __float2bfloat16(a0[px]);
        __hip_bfloat16 h1 = __float2bfloat16(a1[px]);
        ushort2 o;
        o.x = *reinterpret_cast<unsigned short*>(&h0);
        o.y = *reinterpret_cast<unsigned short*>(&h1);
        fp[(size_t)px * 128] = o;
    }
}

// ---------------- head layer 1: 1x1 conv, 8-wave pipelined -------------
// GEMM M=256, N=80000 (313 tiles of 256, tail-guarded), K=256 (8 steps).
__global__ __launch_bounds__(512, 2) void head1_mfma8(
    const __hip_bfloat16* __restrict__ f,   // [N][256]
    const __hip_bfloat16* __restrict__ w1,  // [256][256] bf16
    const float* __restrict__ g, const float* __restrict__ bb,
    const float* __restrict__ mm_, const float* __restrict__ vv,
    __hip_bfloat16* __restrict__ h)         // [N][256]
{
    constexpr int NTOT = 80000;
    const int n0  = blockIdx.x * 256;
    const int tid = threadIdx.x;
    const int wid = tid >> 6, lane = tid & 63;
    const int wr = wid >> 2, wc = wid & 3;

    __shared__ __align__(16) __hip_bfloat16 lA[4 * 8192];
    __shared__ __align__(16) __hip_bfloat16 lB[4 * 8192];

    const int arow = tid >> 2;
    const int seg  = (tid & 3) ^ ((tid >> 3) & 3);

    const size_t wbase0 = (size_t)arow * 256 + seg * 8;
    const size_t wbase1 = (size_t)(arow + 128) * 256 + seg * 8;
    int nr0 = n0 + arow;       if (nr0 > NTOT - 1) nr0 = NTOT - 1;
    int nr1 = n0 + arow + 128; if (nr1 > NTOT - 1) nr1 = NTOT - 1;
    const size_t xbase0 = (size_t)nr0 * 256 + seg * 8;
    const size_t xbase1 = (size_t)nr1 * 256 + seg * 8;

    auto stage = [&](int c0, int sel) {
        char* a0 = (char*)lA + sel * 16384 + wid * 1024;
        char* b0p = (char*)lB + sel * 16384 + wid * 1024;
        gld_lds16(w1 + wbase0 + c0, a0);
        gld_lds16(w1 + wbase1 + c0, a0 + 8192);
        gld_lds16(f + xbase0 + c0, b0p);
        gld_lds16(f + xbase1 + c0, b0p + 8192);
    };

    f32x4 acc[8][4];
#pragma unroll
    for (int i = 0; i < 8; ++i)
#pragma unroll
        for (int j = 0; j < 4; ++j)
            acc[i][j] = f32x4{0.f, 0.f, 0.f, 0.f};

    const int l15 = lane & 15, l16 = lane >> 4;
    const int slot = l16 ^ ((l15 >> 1) & 3);
    const int aoff = (wr * 128 + l15) * 32 + slot * 8;
    const int boff = (wc * 64  + l15) * 32 + slot * 8;

    bf16x8 pA0[4], pA4[4], pB[4], qA0[4], qA4[4], qB[4];

    stage(0, 0); stage(32, 1); stage(64, 2);
    WAITVM8; BAR();
    RD8(pA0, pB, 0);

    STEP(pA0, pA4, pB, qA0, qB, 0, stage(96, 3),  WAITVM8, true);   // t=0
    STEP(qA0, qA4, qB, pA0, pB, 1, stage(128, 0), WAITVM8, true);   // t=1
    STEP(pA0, pA4, pB, qA0, qB, 2, stage(160, 1), WAITVM8, true);   // t=2
    STEP(qA0, qA4, qB, pA0, pB, 3, stage(192, 2), WAITVM8, true);   // t=3
    STEP(pA0, pA4, pB, qA0, qB, 0, stage(224, 3), WAITVM8, true);   // t=4
    STEP(qA0, qA4, qB, pA0, pB, 1, (void)0,       WAITVM4, true);   // t=5
    STEP(pA0, pA4, pB, qA0, qB, 2, (void)0,       WAITVM0, true);   // t=6
    STEP(qA0, qA4, qB, pA0, pB, 3, (void)0,       (void)0, false);  // t=7

#pragma unroll
    for (int i = 0; i < 8; ++i) {
        const int co_b = wr * 128 + i * 16 + l16 * 4;
        float sc[4], sh[4];
#pragma unroll
        for (int r = 0; r < 4; ++r) {
            sc[r] = g[co_b + r] * rsqrtf(vv[co_b + r] + EPS);
            sh[r] = bb[co_b + r] - mm_[co_b + r] * sc[r];
        }
#pragma unroll
        for (int jj = 0; jj < 4; ++jj) {
            const int n = n0 + wc * 64 + jj * 16 + l15;
            if (n < NTOT) {
                u16x4 o;
#pragma unroll
                for (int r = 0; r < 4; ++r) {
                    const float v = fmaxf(fmaf(acc[i][jj][r], sc[r], sh[r]), 0.f);
                    __hip_bfloat16 hv = __float2bfloat16(v);
                    o[r] = *reinterpret_cast<unsigned short*>(&hv);
                }
                *reinterpret_cast<u16x4*>(&h[(size_t)n * 256 + co_b]) = o;
            }
        }
    }
}

// ---------------- head layer 2: 1x1 conv (256 -> 10) + bias, NCHW out --------
__global__ __launch_bounds__(256) void head2(
    const __hip_bfloat16* __restrict__ h,  // [N][256]
    const float* __restrict__ w2,          // [10][256]
    const float* __restrict__ b2,          // [10]
    float* __restrict__ out)               // [B][10][25][25]
{
    const int py = blockIdx.x, b = blockIdx.y;
    __shared__ __hip_bfloat16 lh[25][258];
    __shared__ float lw[10][256];

    const __hip_bfloat16* hp = h + ((size_t)b * 625 + (size_t)py * 25) * 256;
    for (int i = threadIdx.x; i < 25 * 256; i += 256) {
        int px = i >> 8, c = i & 255;
        lh[px][c] = hp[i];
    }
    for (int i = threadIdx.x; i < 10 * 256; i += 256)
        lw[i >> 8][i & 255] = w2[i];
    __syncthreads();

    if (threadIdx.x < 250) {
        const int o = threadIdx.x / 25, px = threadIdx.x % 25;
        float a = b2[o];
        for (int c = 0; c < 256; ++c)
            a = fmaf(__bfloat162float(lh[px][c]), lw[o][c], a);
        out[(((size_t)b * 10 + o) * 25 + py) * 25 + px] = a;
    }
}

extern "C" void kernel_launch(void* const* d_in, const int* in_sizes, int n_in,
                              void* d_out, int out_size, void* d_ws, size_t ws_size,
                              hipStream_t stream) {
    const float* kernel = (const float*)d_in[0];   // [128,256,7,7]
    const float* search = (const float*)d_in[1];   // [128,256,31,31]
    const float* w_ck   = (const float*)d_in[2];
    const float* g1 = (const float*)d_in[3];
    const float* b1 = (const float*)d_in[4];
    const float* m1 = (const float*)d_in[5];
    const float* v1 = (const float*)d_in[6];
    const float* w_cs   = (const float*)d_in[7];
    const float* g2 = (const float*)d_in[8];
    const float* b2 = (const float*)d_in[9];
    const float* m2 = (const float*)d_in[10];
    const float* v2 = (const float*)d_in[11];
    const float* w_h1   = (const float*)d_in[12];
    const float* g3 = (const float*)d_in[13];
    const float* b3 = (const float*)d_in[14];
    const float* m3 = (const float*)d_in[15];
    const float* v3 = (const float*)d_in[16];
    const float* w_h2   = (const float*)d_in[17];
    const float* b_h2   = (const float*)d_in[18];

    float* out = (float*)d_out;

    __hip_bfloat16* ws = (__hip_bfloat16*)d_ws;
    __hip_bfloat16* y1    = ws;
    __hip_bfloat16* y2    = ws + (size_t)819200;
    float*          part  = (float*)(ws + (size_t)819200);
    __hip_bfloat16* wt_ck = ws + (size_t)28377088;
    __hip_bfloat16* wt_cs = ws + (size_t)28966912;
    __hip_bfloat16* wh1   = ws + (size_t)29556736;
    __hip_bfloat16* xt_k  = ws + (size_t)29622272;
    __hip_bfloat16* xt_s  = ws + (size_t)31227904;
    __hip_bfloat16* feat  = ws + (size_t)29622272;
    __hip_bfloat16* h     = ws + (size_t)819200;

    (void)in_sizes; (void)n_in; (void)out_size; (void)ws_size;

    // pre-passes
    wt_transpose_bf16<<<256, 256, 0, stream>>>(w_ck, wt_ck);
    wt_transpose_bf16<<<256, 256, 0, stream>>>(w_cs, wt_cs);
    f32_to_bf16<<<256, 256, 0, stream>>>(w_h1, wh1, 65536);
    nchw_to_nhwc_v2<<<dim3(2, 128), 256, 0, stream>>>(kernel, xt_k, 49);
    nchw_to_nhwc_v2<<<dim3(31, 128), 256, 0, stream>>>(search, xt_s, 961);

    // kernel branch: split-K x4 partials (into y2 region) + reduce -> y1
    conv3x3_partial<<<dim3(25, 4), 256, 0, stream>>>(xt_k, wt_ck, part);
    reduce_bn_relu<<<3200, 256, 0, stream>>>(part, g1, b1, m1, v1, y1);

    // search branch: pipelined implicit GEMM -> y2 (N=107648, 421 tiles)
    conv3x3_mfma8<31, 31, 107648><<<421, 512, 0, stream>>>(
        xt_s, wt_cs, g2, b2, m2, v2, y2);

    // depthwise xcorr -> feat NHWC
    xcorr_dw_nhwc2<<<dim3(25, 128), 128, 0, stream>>>(y2, y1, feat);

    // head
    head1_mfma8<<<313, 512, 0, stream>>>(feat, wh1, g3, b3, m3, v3, h);
    head2<<<dim3(25, 128), 256, 0, stream>>>(h, w_h2, b_h2, out);
}